// Round 6
// baseline (793.933 us; speedup 1.0000x reference)
//
#include <hip/hip_runtime.h>
#include <hip/hip_bf16.h>

// ---------------------------------------------------------------------------
// CombineMultiOutputModelWeightedConcat — MFMA pipeline, r6.
// r6: REG path — barrier-free K-loop. r5 counters: top stage (D) at
// MfmaUtil 7.5%, HBM 20%, occ 24% = latency-bound; the LDS-staged loop's
// vmcnt(0)+barrier locks all 4 waves/block into ~2-3 streams/CU. Since each
// MFMA fragment is 16 rows x 64B contiguous in global (k-major layout, same
// 16-line/instr cost as global_load_lds staging), A/B fragments now load
// straight to VGPRs: no K-loop LDS, no barriers -> 12 independent
// wave-streams/CU. LDS reuse (2x per tile) handed to L1/L2.
// Stage A keeps LDS path (VALU dtype convert). Epilogue: r5's LDS-transpose
// vectorized store (verified: WRITE_SIZE dropped to exactly logical).
// Stats: partC/partH partial-write + reduce. gate/heads: blocked GEMV.
// ---------------------------------------------------------------------------

typedef unsigned short u16;
typedef _Float16 f16x8 __attribute__((ext_vector_type(8)));
typedef float f32x4 __attribute__((ext_vector_type(4)));

#define B_ROWS 32768
#define EPS_BN 0.2f
#define BINV (1.0f / 32768.0f)

__device__ __forceinline__ float bf2f(u16 u) {
    union { unsigned int i; float f; } c;
    c.i = ((unsigned int)u) << 16;
    return c.f;
}
__device__ __forceinline__ u16 f2bf(float f) {
    union { float f; unsigned int i; } c;
    c.f = f;
    unsigned int x = c.i;
    return (u16)((x + 0x7FFFu + ((x >> 16) & 1u)) >> 16);
}
__device__ __forceinline__ float h2f(u16 u) {
    _Float16 h;
    __builtin_memcpy(&h, &u, 2);
    return (float)h;
}
__device__ __forceinline__ u16 f2h(float f) {
    _Float16 h = (_Float16)f;
    u16 u;
    __builtin_memcpy(&u, &h, 2);
    return u;
}
__device__ __forceinline__ float ldp(const void* p, long i, int flag) {
    return flag ? bf2f(((const u16*)p)[i]) : ((const float*)p)[i];
}
// async global->LDS, 16B per lane; lds base wave-uniform, lane i lands at +16i
__device__ __forceinline__ void gload16(const u16* gp, u16* lp) {
    __builtin_amdgcn_global_load_lds(
        (const __attribute__((address_space(1))) unsigned int*)gp,
        (__attribute__((address_space(3))) unsigned int*)lp, 16, 0, 0);
}

// --------------------------------------------------------------------------
__global__ void detect_dtype(const u16* __restrict__ x, int* __restrict__ flag) {
    const int lane = threadIdx.x;  // 64 threads
    const u16 v = x[2 * lane];
    const int e = (v >> 7) & 0xFF;
    const bool plausible = (e >= 110 && e <= 140);
    const unsigned long long m = __ballot(plausible);
    if (lane == 0) *flag = (__popcll(m) >= 58) ? 1 : 0;
}

struct PTab { const void* p[20]; int n[20]; int off[20]; };

__global__ void convert_params(PTab t, float* __restrict__ dst,
                               const int* __restrict__ flag) {
    const int ti = blockIdx.y;
    const int n = t.n[ti];
    float* o = dst + t.off[ti];
    const int isbf = *flag;
    for (int i = blockIdx.x * 256 + threadIdx.x; i < n; i += gridDim.x * 256)
        o[i] = ldp(t.p[ti], i, isbf);
}

// ---------------------------------------------------------------------------
// prep_w: Wt[inst][n][k] = f16(s_k * W[k][n]);  T0/T1[n] = sum_{k<,>=khalf}
// t_k*W[k][n];  biasP = bias;  bsum = bias+T0+T1.
// ---------------------------------------------------------------------------
__global__ __launch_bounds__(256) void prep_w(
    const void* __restrict__ W, long wstride,
    const void* __restrict__ bias, long bstride,
    const float* __restrict__ psum, const float* __restrict__ psq, int pstride,
    const void* __restrict__ pg, const void* __restrict__ pbe, int gmask,
    const int* __restrict__ dtflag,
    u16* __restrict__ Wt, long wtstride,
    float* __restrict__ biasP, float* __restrict__ T0o,
    float* __restrict__ T1o, float* __restrict__ bsum, long bost,
    int K, int khalf)
{
    const int tid = threadIdx.x;
    const int n = blockIdx.x;
    const int N = gridDim.x;
    const int inst = blockIdx.y;
    const int flag = *dtflag;
    __shared__ float sn[512], tn[512];
    __shared__ float r0[4], r1[4];

    for (int i = tid; i < K; i += 256) {
        float s = 1.f, t = 0.f;
        if (psum) {
            float m = psum[(long)pstride * inst + i] * BINV;
            float v = psq[(long)pstride * inst + i] * BINV - m * m;
            float g = ldp(pg, i & gmask, flag);
            float b = ldp(pbe, i & gmask, flag);
            s = g * rsqrtf(v + EPS_BN);
            t = b - m * s;
        }
        sn[i] = s; tn[i] = t;
    }
    __syncthreads();
    float p0 = 0.f, p1 = 0.f;
    for (int k = tid; k < K; k += 256) {
        float wv = ldp(W, wstride * inst + (long)k * N + n, flag);
        Wt[wtstride * inst + (long)n * K + k] = f2h(sn[k] * wv);
        float tw = tn[k] * wv;
        if (k < khalf) p0 += tw; else p1 += tw;
    }
#pragma unroll
    for (int off = 32; off; off >>= 1) {
        p0 += __shfl_xor(p0, off);
        p1 += __shfl_xor(p1, off);
    }
    const int lane = tid & 63, wid = tid >> 6;
    if (lane == 0) { r0[wid] = p0; r1[wid] = p1; }
    __syncthreads();
    if (tid == 0) {
        float t0 = r0[0] + r0[1] + r0[2] + r0[3];
        float t1 = r1[0] + r1[1] + r1[2] + r1[3];
        float bp = ldp(bias, bstride * inst + n, flag);
        long o = bost * inst + n;
        biasP[o] = bp; T0o[o] = t0; T1o[o] = t1; bsum[o] = bp + t0 + t1;
    }
}

// ---------------------------------------------------------------------------
// reduce_stats: sum per-block stat partials into stats arrays.
// part layout: [p = inst*gridY + by][x = bx][{sum[colsPer], sq[colsPer]}].
// ---------------------------------------------------------------------------
__global__ __launch_bounds__(256) void reduce_stats(
    const float* __restrict__ part, int X, int colsPer,
    float* __restrict__ outS, float* __restrict__ outQ, int total)
{
    const int t = blockIdx.x * 256 + threadIdx.x;
    if (t >= total) return;
    const int p = t / colsPer, c = t % colsPer;
    const float* pb = part + (long)p * X * 2 * colsPer + c;
    float s = 0.f, q = 0.f;
#pragma unroll 4
    for (int x = 0; x < X; ++x) {
        s += pb[(long)x * 2 * colsPer];
        q += pb[(long)x * 2 * colsPer + colsPer];
    }
    outS[t] = s; outQ[t] = q;
}

// ---------------------------------------------------------------------------
// MFMA GEMM. Block tile (WM*64) x (WN*64), 256 threads = 4 waves WM x WN
// (each wave 64x64 = 4x4 of 16x16x32, 64 AGPR acc).
// REG path (!XSTAGE): fragments load straight global->VGPR (16 rows x 64B
// contiguous per instruction), NO K-loop LDS, NO barriers — every wave an
// independent latency-hiding stream.
// XSTAGE path: LDS staging with VALU dtype convert (swizzled, as r5).
// Epilogue: bias/gate + relu + stats, transpose via wave's LDS slice,
// 8 x dwordx4/lane contiguous stores.
// ---------------------------------------------------------------------------
template <bool XSTAGE, bool ROWW, int WM, int WN, int K>
__global__ __launch_bounds__(256, 3) void gemm_mfma(
    const void* __restrict__ X, const void* __restrict__ X2,
    long xstride, int ximask, int ldx, int ksplit, long ksecond,
    const int* __restrict__ dtflag,
    const u16* __restrict__ Wt, long wtstride,
    const float* __restrict__ biasP, const float* __restrict__ T0,
    const float* __restrict__ T1, const float* __restrict__ bsum, int bN,
    u16* __restrict__ Out, long ostride, int ldout,
    float* __restrict__ gsum, float* __restrict__ gsq, int sstride,
    float* __restrict__ part,
    const float* __restrict__ Y0v)
{
    const int tid = threadIdx.x;
    const int lane = tid & 63;
    const int wid = tid >> 6;
    const int wm = wid / WN, wn = wid % WN;
    const int inst = blockIdx.z;
    const int rowB = blockIdx.x * (64 * WM);
    const int nBase = blockIdx.y * (64 * WN);
    const int n0 = nBase + wn * 64;
    const int fm = lane & 15, quad = lane >> 4;

    // LDS: staging (XSTAGE K-loop) / per-wave epilogue transpose tiles
    __shared__ __align__(16) u16 AsBs[(WM + WN) * 4096];
    __shared__ float redS[4][64];
    __shared__ float redQ[4][64];

    bool xf32 = false;
    if constexpr (XSTAGE) xf32 = (*dtflag == 0);
    const char* xb;
    if (XSTAGE) xb = (const char*)(inst == 0 ? X : X2);
    else        xb = (const char*)X + 2l * xstride * (inst & ximask);
    const u16* wtp = Wt + wtstride * inst;
    u16* op = Out + ostride * inst;

    f32x4 acc[4][4];
#pragma unroll
    for (int i = 0; i < 4; ++i)
#pragma unroll
        for (int j = 0; j < 4; ++j) acc[i][j] = (f32x4){0.f, 0.f, 0.f, 0.f};

    _Float16 ysc[2][4];
    if constexpr (ROWW) {
        const float* yp = Y0v + (long)inst * B_ROWS;
#pragma unroll
        for (int mi = 0; mi < 4; ++mi) {
            const float y = yp[rowB + wm * 64 + mi * 16 + fm];
            ysc[0][mi] = (_Float16)y;
            ysc[1][mi] = (_Float16)(1.f - y);
        }
    }

    if constexpr (!XSTAGE) {
        // ---- REG path: barrier-free K-loop, fragments global->VGPR ----
        long aOff[4], bOff[4];
#pragma unroll
        for (int mi = 0; mi < 4; ++mi)
            aOff[mi] = (long)(rowB + wm * 64 + mi * 16 + fm) * ldx;
#pragma unroll
        for (int ni = 0; ni < 4; ++ni)
            bOff[ni] = (long)(n0 + ni * 16 + fm) * K;
        const u16* xs0 = (const u16*)xb;

        for (int kt = 0; kt < K / 64; ++kt) {
            const int kk = kt * 64;
            const u16* xs = xs0;
            int kkr = kk;
            if (kk >= ksplit) { xs += ksecond; kkr -= ksplit; }
            const int sel = (ROWW && kk >= ksplit) ? 1 : 0;
#pragma unroll
            for (int q = 0; q < 2; ++q) {
                const int kc = (q * 4 + quad) * 8;
                f16x8 af[4], bfr[4];
#pragma unroll
                for (int mi = 0; mi < 4; ++mi)
                    af[mi] = *(const f16x8*)(xs + aOff[mi] + kkr + kc);
#pragma unroll
                for (int ni = 0; ni < 4; ++ni)
                    bfr[ni] = *(const f16x8*)(wtp + bOff[ni] + kk + kc);
                if constexpr (ROWW) {
#pragma unroll
                    for (int mi = 0; mi < 4; ++mi) {
                        const _Float16 yh = ysc[sel][mi];
#pragma unroll
                        for (int j = 0; j < 8; ++j) af[mi][j] *= yh;
                    }
                }
#pragma unroll
                for (int mi = 0; mi < 4; ++mi)
#pragma unroll
                    for (int ni = 0; ni < 4; ++ni)
                        acc[mi][ni] = __builtin_amdgcn_mfma_f32_16x16x32_f16(
                            af[mi], bfr[ni], acc[mi][ni], 0, 0, 0);
            }
        }
    } else {
        // ---- XSTAGE path: LDS staging with VALU convert (r5 structure) ----
        u16* As = AsBs;
        u16* Bs = AsBs + WM * 4096;
        const int rloc = lane >> 3;
        const int cg = (lane & 7) ^ rloc;
        for (int kt = 0; kt < K / 64; ++kt) {
            const int kk = kt * 64;
            __syncthreads();
#pragma unroll
            for (int p = 0; p < WM * 2; ++p) {
                const int s = p * 256 + tid;       // chunk id
                const int m = s >> 3, c = s & 7;
                const int g = c ^ (m & 7);
                f16x8 h;
                if (xf32) {
                    const float* gp = (const float*)xb + (long)(rowB + m) * ldx + kk + g * 8;
                    const float4 u = *(const float4*)gp;
                    const float4 u2 = *(const float4*)(gp + 4);
                    h[0] = (_Float16)u.x;  h[1] = (_Float16)u.y;
                    h[2] = (_Float16)u.z;  h[3] = (_Float16)u.w;
                    h[4] = (_Float16)u2.x; h[5] = (_Float16)u2.y;
                    h[6] = (_Float16)u2.z; h[7] = (_Float16)u2.w;
                } else {
                    const uint4 v = *(const uint4*)((const u16*)xb + (long)(rowB + m) * ldx + kk + g * 8);
                    const u16* pv = (const u16*)&v;
#pragma unroll
                    for (int j = 0; j < 8; ++j) h[j] = (_Float16)bf2f(pv[j]);
                }
                *(f16x8*)&As[s * 8] = h;
            }
#pragma unroll
            for (int s = wid; s < WN * 8; s += 4)
                gload16(wtp + (long)(nBase + s * 8 + rloc) * K + kk + cg * 8,
                        &Bs[s * 512 + lane * 8]);
            __syncthreads();

#pragma unroll
            for (int q = 0; q < 2; ++q) {
                f16x8 af[4], bfr[4];
#pragma unroll
                for (int mi = 0; mi < 4; ++mi) {
                    const int mm = wm * 64 + mi * 16 + fm;
                    af[mi] = *(const f16x8*)&As[mm * 64 + (((q * 4 + quad) ^ (mm & 7)) * 8)];
                }
#pragma unroll
                for (int ni = 0; ni < 4; ++ni) {
                    const int nn = wn * 64 + ni * 16 + fm;
                    bfr[ni] = *(const f16x8*)&Bs[nn * 64 + (((q * 4 + quad) ^ (nn & 7)) * 8)];
                }
#pragma unroll
                for (int mi = 0; mi < 4; ++mi)
#pragma unroll
                    for (int ni = 0; ni < 4; ++ni)
                        acc[mi][ni] = __builtin_amdgcn_mfma_f32_16x16x32_f16(
                            af[mi], bfr[ni], acc[mi][ni], 0, 0, 0);
            }
        }
    }

    __syncthreads();   // K-loop LDS dead; reuse as epilogue tiles

    // ---- epilogue phase 1: bias/relu/stats + transpose into wave's LDS ----
    // wave tile: u16[64][64], chunk-swizzled col ^= ((row>>1)&7)<<3
    u16* wtile = AsBs + wid * 4096;
    const int R0 = rowB + wm * 64;

    float yv[16];
    if constexpr (ROWW) {
        const float* yp = Y0v + (long)inst * B_ROWS;
#pragma unroll
        for (int mi = 0; mi < 4; ++mi)
#pragma unroll
            for (int r = 0; r < 4; ++r)
                yv[mi * 4 + r] = yp[R0 + mi * 16 + quad * 4 + r];
    }

#pragma unroll
    for (int ni = 0; ni < 4; ++ni) {
        const int nc = ni * 16 + fm;
        const int n = n0 + nc;
        float bS = 0.f, bP = 0.f, t0v = 0.f, t1v = 0.f;
        if constexpr (ROWW) {
            bP = biasP[(long)inst * bN + n];
            t0v = T0[(long)inst * bN + n];
            t1v = T1[(long)inst * bN + n];
        } else {
            bS = bsum[(long)inst * bN + n];
        }
        float s = 0.f, qq = 0.f;
#pragma unroll
        for (int mi = 0; mi < 4; ++mi) {
#pragma unroll
            for (int r = 0; r < 4; ++r) {
                float v;
                if constexpr (ROWW) {
                    const float y = yv[mi * 4 + r];
                    v = acc[mi][ni][r] + y * t0v + (1.f - y) * t1v + bP;
                } else {
                    v = acc[mi][ni][r] + bS;
                }
                v = fmaxf(v, 0.f);
                s += v; qq += v * v;
                const int lr = mi * 16 + quad * 4 + r;
                wtile[lr * 64 + (nc ^ (((lr >> 1) & 7) << 3))] = f2h(v);
            }
        }
        s += __shfl_xor(s, 16);  s += __shfl_xor(s, 32);
        qq += __shfl_xor(qq, 16); qq += __shfl_xor(qq, 32);
        if (quad == 0) { redS[wid][nc] = s; redQ[wid][nc] = qq; }
    }

    // ---- epilogue phase 2: coalesced 16B/lane stores from LDS ----
    {
        const int l8 = lane & 7, r8 = lane >> 3;
#pragma unroll
        for (int it = 0; it < 8; ++it) {
            const int lr = it * 8 + r8;
            const int ch = l8 ^ ((lr >> 1) & 7);
            const f16x8 hv = *(const f16x8*)&wtile[lr * 64 + ch * 8];
            *(f16x8*)(op + (long)(R0 + lr) * ldout + n0 + l8 * 8) = hv;
        }
    }

    __syncthreads();
    if (tid < WN * 64) {
        const int wnc = tid >> 6, within = tid & 63;
        float s = 0.f, q = 0.f;
#pragma unroll
        for (int w = 0; w < WM; ++w) {
            s += redS[w * WN + wnc][within];
            q += redQ[w * WN + wnc][within];
        }
        if (part) {
            // per-block partial (coalesced, no atomics); reduce_stats sums.
            float* pb = part +
                (long)((inst * gridDim.y + blockIdx.y) * gridDim.x + blockIdx.x)
                    * (2 * WN * 64);
            pb[tid] = s;
            pb[WN * 64 + tid] = q;
        } else {
            atomicAdd(&gsum[(long)inst * sstride + nBase + tid], s);
            atomicAdd(&gsq [(long)inst * sstride + nBase + tid], q);
        }
    }
}

// ---------------------------------------------------------------------------
// gate_kernel: blocked GEMV, BN folded into LDS-resident scaled weights.
// Block = 256 threads = 128 rows x 2 col-segments (32 cols each).
// ---------------------------------------------------------------------------
__global__ __launch_bounds__(256) void gate_kernel(
    const u16* __restrict__ zc,
    const float* __restrict__ stFs, const float* __restrict__ stFq,
    const float* __restrict__ g4, const float* __restrict__ be4,
    const float* __restrict__ Wy, const float* __restrict__ by,
    float* __restrict__ Y0)
{
    const int tid = threadIdx.x;
    const int k = blockIdx.y;
    const int r0 = blockIdx.x * 128;

    __shared__ __align__(8) float Ws2[64][2];
    __shared__ float cg[2];

    // ---- fold BN into weights (one column per lane, first wave) ----
    if (tid < 64) {
        const int c = tid;
        const float m = stFs[k * 64 + c] * BINV;
        const float v = stFq[k * 64 + c] * BINV - m * m;
        const float s = g4[c] * rsqrtf(v + EPS_BN);
        const float t = be4[c] - m * s;
        const float w0 = Wy[k * 128 + c * 2 + 0];
        const float w1 = Wy[k * 128 + c * 2 + 1];
        Ws2[c][0] = s * w0;
        Ws2[c][1] = s * w1;
        float t0 = t * w0, t1 = t * w1;
#pragma unroll
        for (int off = 32; off; off >>= 1) {
            t0 += __shfl_xor(t0, off);
            t1 += __shfl_xor(t1, off);
        }
        if (c == 0) {
            cg[0] = t0 + by[k * 2 + 0];
            cg[1] = t1 + by[k * 2 + 1];
        }
    }
    __syncthreads();

    // ---- GEMV: 1 row / 2 threads, 32 columns each ----
    const int row = r0 + (tid >> 1);
    const int seg = tid & 1;
    const u16* xp = zc + ((long)k * B_ROWS + row) * 64 + seg * 32;
    float a0 = 0.f, a1 = 0.f;
#pragma unroll
    for (int it = 0; it < 4; ++it) {
        const uint4 v = *(const uint4*)(xp + it * 8);
        const u16* pv = (const u16*)&v;
#pragma unroll
        for (int e = 0; e < 8; ++e) {
            const int c = seg * 32 + it * 8 + e;
            const float x = h2f(pv[e]);
            a0 += x * Ws2[c][0];
            a1 += x * Ws2[c][1];
        }
    }
    a0 += __shfl_xor(a0, 1);
    a1 += __shfl_xor(a1, 1);
    if (seg == 0) {
        const float l0 = a0 + cg[0];
        const float l1 = a1 + cg[1];
        Y0[(long)k * B_ROWS + row] = 1.f / (1.f + __expf(l1 - l0));
    }
}

// ---------------------------------------------------------------------------
// heads_kernel: blocked GEMV, BN folded into LDS weight table Ws[256][8]
// (fp32, XOR-swizzled row index so 4 concurrent col-segments hit distinct
// bank groups). Block = 256 threads = 64 rows x 4 segments (64 cols).
// ---------------------------------------------------------------------------
__global__ __launch_bounds__(256) void heads_kernel(
    const u16* __restrict__ zxc,
    const float* __restrict__ stHs, const float* __restrict__ stHq,
    const float* __restrict__ g1, const float* __restrict__ be1,
    const float* __restrict__ Wo1, const float* __restrict__ bo1,
    const float* __restrict__ Wo2, const float* __restrict__ bo2,
    const float* __restrict__ Wo3, const float* __restrict__ bo3,
    const float* __restrict__ Wo4, const float* __restrict__ bo4,
    void* __restrict__ out, const int* __restrict__ dtflag)
{
    const int tid = threadIdx.x;
    const int k = blockIdx.y;
    const int r0 = blockIdx.x * 64;

    const float* Wo; const float* bo; int nk; long obase;
    if (k == 0)      { Wo = Wo1; bo = bo1; nk = 3; obase = 0; }
    else if (k == 1) { Wo = Wo2; bo = bo2; nk = 3; obase = (long)3 * B_ROWS; }
    else if (k == 2) { Wo = Wo3; bo = bo3; nk = 6; obase = (long)6 * B_ROWS; }
    else             { Wo = Wo4; bo = bo4; nk = 4; obase = (long)12 * B_ROWS; }

    __shared__ __align__(16) float Ws[256][8];
    __shared__ float cj[8];
    __shared__ float redC[4][8];

    // ---- fold BN into weights (one column per thread) ----
    {
        const int c = tid;
        const float m = stHs[k * 256 + c] * BINV;
        const float v = stHq[k * 256 + c] * BINV - m * m;
        const float s = g1[c] * rsqrtf(v + EPS_BN);
        const float t = be1[c] - m * s;
        const int rs = c ^ (c >> 6);       // bank-group swizzle
        float tw[6];
#pragma unroll
        for (int j = 0; j < 6; ++j) {
            const float w = (j < nk) ? Wo[c * nk + j] : 0.f;
            Ws[rs][j] = s * w;
            tw[j] = t * w;
        }
        Ws[rs][6] = 0.f; Ws[rs][7] = 0.f;
#pragma unroll
        for (int off = 32; off; off >>= 1)
#pragma unroll
            for (int j = 0; j < 6; ++j) tw[j] += __shfl_xor(tw[j], off);
        const int lane = tid & 63, wid = tid >> 6;
        if (lane < 6) redC[wid][lane] = tw[lane];
    }
    __syncthreads();
    if (tid < 8) {
        float s4 = 0.f;
        if (tid < 6) s4 = redC[0][tid] + redC[1][tid] + redC[2][tid] + redC[3][tid];
        cj[tid] = (tid < nk) ? s4 + bo[tid] : 0.f;
    }
    __syncthreads();

    // ---- GEMV: 1 row / 4 threads, 64 columns each ----
    const int row = r0 + (tid >> 2);
    const int seg = tid & 3;
    const u16* xp = zxc + ((long)k * B_ROWS + row) * 256 + seg * 64;
    float acc[6];
#pragma unroll
    for (int j = 0; j < 6; ++j) acc[j] = 0.f;
#pragma unroll
    for (int it = 0; it < 8; ++it) {
        const uint4 v = *(const uint4*)(xp + it * 8);
        const u16* pv = (const u16*)&v;
#pragma unroll
        for (int e = 0; e < 8; ++e) {
            const int cc = it * 8 + e;             // column within segment
            const int rs = (seg * 64 + cc) ^ seg;  // swizzled LDS row
            const float x = h2f(pv[e]);
            const f32x4 w0 = *(const f32x4*)&Ws[rs][0];
            const f32x4 w1 = *(const f32x4*)&Ws[rs][4];
            acc[0] += x * w0[0];
            acc[1] += x * w0[1];
            acc[2] += x * w0[2];
            acc[3] += x * w0[3];
            acc[4] += x * w1[0];
            acc[5] += x * w1[1];
        }
    }
#pragma unroll
    for (int j = 0; j < 6; ++j) {
        acc[j] += __shfl_xor(acc[j], 1);
        acc[j] += __shfl_xor(acc[j], 2);
    }

    if (seg == 0) {
        float l[6];
        float mx = -1e30f;
#pragma unroll
        for (int j = 0; j < 6; j++)
            if (j < nk) { l[j] = acc[j] + cj[j]; mx = fmaxf(mx, l[j]); }
        float e[6];
        float se = 0.f;
#pragma unroll
        for (int j = 0; j < 6; j++)
            if (j < nk) { e[j] = __expf(l[j] - mx); se += e[j]; }
        const float inv = 1.f / se;
        if (*dtflag) {
            u16* ob = (u16*)out;
#pragma unroll
            for (int j = 0; j < 6; j++)
                if (j < nk) ob[obase + (long)row * nk + j] = f2bf(e[j] * inv);
        } else {
            float* of = (float*)out;
#pragma unroll
            for (int j = 0; j < 6; j++)
                if (j < nk) of[obase + (long)row * nk + j] = e[j] * inv;
        }
    }
}

__global__ void fill_sentinel(u16* out, int n) {
    int i = blockIdx.x * 256 + threadIdx.x;
    if (i < n) out[i] = 0x3E80;
}

// ---------------------------------------------------------------------------
extern "C" void kernel_launch(void* const* d_in, const int* in_sizes, int n_in,
                              void* d_out, int out_size, void* d_ws, size_t ws_size,
                              hipStream_t stream)
{
    const long B = B_ROWS;
    char* ws = (char*)d_ws;
    const size_t MB = 1024 * 1024;

    // Lifetime-aliased activation layout (fp16)
    u16* z1  = (u16*)(ws);                      // [2][B][256]  (0..32MB)
    u16* z2  = (u16*)(ws + 32 * MB);            // [2][B][256]  (32..64MB)
    u16* za  = (u16*)(ws);                      // [4][B][128]  (0..32MB)
    u16* zbb = (u16*)(ws + 32 * MB);            // [4][B][64]   (32..48MB)
    u16* zc  = (u16*)(ws + 48 * MB);            // [4][B][64]   (48..64MB)
    u16* zxc = (u16*)(ws);                      // [4][B][256]  (0..64MB!)
    u16* zb  = (u16*)(ws + 64 * MB);            // [k][s][B][256] (64..192MB)
    float* Y0 = (float*)(ws + 192 * MB);                   // 512 KB
    float* stats = (float*)(ws + 192 * MB + 512 * 1024);   // 40 KB
    int* dtflag = (int*)(ws + 192 * MB + 576 * 1024);
    float* Pst = (float*)(ws + 192 * MB + 640 * 1024);     // small fp32 params

    // Wt region (fp16, prescaled+transposed weights)
    u16* WtA = (u16*)(ws + 193 * MB);                 // [256][512]     (+0..256KB)
    u16* WtB = WtA + 131072;                          // [2][256][256]  (+256..512KB)
    u16* WtC = WtB + 131072;                          // [8][256][256]  (+512KB..1.5MB)
    u16* WtD = WtC + 524288;                          // [4][128][512]  (+1.5..2MB)
    u16* WtH = WtD + 262144;                          // [4][256][512]  (+2..3MB)
    u16* WtE = WtH + 524288;                          // [4][64][128]
    u16* WtF = WtE + 32768;                           // [4][64][64]
    float* biasArea = (float*)(ws + 197 * MB);
    float* bA = biasArea;        // 2048
    float* bB = bA + 2048;       // 2048
    float* bC = bB + 2048;       // 8192
    float* bD = bC + 8192;       // 2048
    float* bH = bD + 2048;       // 4096
    float* bE = bH + 4096;       // 1024
    float* bF = bE + 1024;       // 1024

    // Stat-partial scratch in lifetime-dead regions:
    //  stage C partials: 4MB at ws+0 (z1 dead after B; za written at D,
    //    after reduce_stats(C)).  SAFE.
    //  stage H partials: 2MB at ws+193MB = WtA..WtD, all dead by stage H.
    float* partC = (float*)(ws);
    float* partH = (float*)(ws + 193 * MB);

    // fp32 param staging (gate/heads consumers)
    const int cIdx[20] = {6,7,10,11,12,13,20,21,22,23,24,25,28,29,30,31,32,33,34,35};
    PTab tab;
    int mapOff[36];
    int acc = 0;
    for (int i = 0; i < 20; i++) {
        tab.p[i] = d_in[cIdx[i]];
        tab.n[i] = in_sizes[cIdx[i]];
        tab.off[i] = acc;
        mapOff[cIdx[i]] = acc;
        acc += in_sizes[cIdx[i]];
    }
    const size_t need = 197 * MB + 20480 * 4 + 4096;
    if (need > ws_size || (size_t)acc * 4 > 384 * 1024) {
        fill_sentinel<<<(out_size + 255) / 256, 256, 0, stream>>>((u16*)d_out, out_size);
        return;
    }
    auto PF = [&](int idx) { return Pst + mapOff[idx]; };

    float* stAs = stats;        float* stAq = stAs + 512;   // [2][256]
    float* stBs = stAq + 512;   float* stBq = stBs + 512;   // [2][256]
    float* stCs = stBq + 512;   float* stCq = stCs + 2048;  // [k][s][256]
    float* stDs = stCq + 2048;  float* stDq = stDs + 512;   // [4][128]
    float* stEs = stDq + 512;   float* stEq = stEs + 256;   // [4][64]
    float* stFs = stEq + 256;   float* stFq = stFs + 256;   // [4][64]
    float* stHs = stFq + 256;   float* stHq = stHs + 1024;  // [4][256]

    hipMemsetAsync(stats, 0, 10240 * 4, stream);
    detect_dtype<<<1, 64, 0, stream>>>((const u16*)d_in[0], dtflag);
    convert_params<<<dim3(32, 20), 256, 0, stream>>>(tab, Pst, dtflag);

    const dim3 blk(256);
    const int BIGK = 1 << 29;  // "never split"

    // ---- Stage A: trunk L1 (dual-dtype X, VALU staging; LDS path) --------
    prep_w<<<dim3(256, 2), blk, 0, stream>>>(
        d_in[2], 0, d_in[3], 0, nullptr, nullptr, 0, nullptr, nullptr, 0,
        dtflag, WtA, 0, bA, bA + 512, bA + 1024, bA + 1536, 256, 512, 512);
    gemm_mfma<true, false, 2, 2, 512><<<dim3(256, 2, 2), blk, 0, stream>>>(
        d_in[0], d_in[1], 0, 0, 512, BIGK, 0, dtflag, WtA, 0,
        bA, bA + 512, bA + 1024, bA + 1536, 256,
        z1, B * 256, 256, stAs, stAq, 256, nullptr, nullptr);

    // ---- Stage B: trunk L2 (norm stA + g1/be1 folded into WtB) -----------
    prep_w<<<dim3(256, 2), blk, 0, stream>>>(
        d_in[4], 0, d_in[5], 0, stAs, stAq, 256, d_in[6], d_in[7], 255,
        dtflag, WtB, 65536, bB, bB + 512, bB + 1024, bB + 1536, 256, 256, 256);
    gemm_mfma<false, false, 2, 2, 256><<<dim3(256, 2, 2), blk, 0, stream>>>(
        z1, nullptr, B * 256, 3, 256, BIGK, 0, dtflag, WtB, 65536,
        bB, bB + 512, bB + 1024, bB + 1536, 256,
        z2, B * 256, 256, stBs, stBq, 256, nullptr, nullptr);

    // ---- Stage C: 8 branch projections (norm stB + g2/be2) ---------------
    for (int s = 0; s < 2; s++) {
        prep_w<<<dim3(256, 4), blk, 0, stream>>>(
            d_in[s ? 16 : 14], 65536, d_in[s ? 17 : 15], 256,
            stBs + s * 256, stBq + s * 256, 0, d_in[8], d_in[9], 255,
            dtflag, WtC + s * 65536, 131072,
            bC + s * 256, bC + 2048 + s * 256, bC + 4096 + s * 256,
            bC + 6144 + s * 256, 512, 256, 256);
    }
    gemm_mfma<false, false, 2, 2, 256><<<dim3(256, 2, 8), blk, 0, stream>>>(
        z2, nullptr, B * 256, 1, 256, BIGK, 0, dtflag, WtC, 65536,
        bC, bC + 2048, bC + 4096, bC + 6144, 256,
        zb, B * 256, 256, stCs, stCq, 256, partC, nullptr);
    reduce_stats<<<dim3(8), blk, 0, stream>>>(partC, 256, 128, stCs, stCq, 2048);

    // ---- Stage D prep+gemm, H prep (stC available) -----------------------
    prep_w<<<dim3(128, 4), blk, 0, stream>>>(
        d_in[18], 65536, d_in[19], 128, stCs, stCq, 512, d_in[6], d_in[7], 255,
        dtflag, WtD, 65536, bD, bD + 512, bD + 1024, bD + 1536, 128, 512, 512);
    prep_w<<<dim3(256, 4), blk, 0, stream>>>(
        d_in[26], 131072, d_in[27], 256, stCs, stCq, 512, d_in[6], d_in[7], 255,
        dtflag, WtH, 131072, bH, bH + 1024, bH + 2048, bH + 3072, 256, 512, 256);
    gemm_mfma<false, false, 2, 2, 512><<<dim3(256, 1, 4), blk, 0, stream>>>(
        zb, nullptr, 2 * B * 256, 3, 256, 256, B * 256, dtflag, WtD, 65536,
        bD, bD + 512, bD + 1024, bD + 1536, 128,
        za, B * 128, 128, stDs, stDq, 128, nullptr, nullptr);

    // ---- Stage E: gating layer b (norm stD + g3/be3) ---------------------
    prep_w<<<dim3(64, 4), blk, 0, stream>>>(
        d_in[20], 8192, d_in[21], 64, stDs, stDq, 128, d_in[10], d_in[11], 127,
        dtflag, WtE, 8192, bE, bE + 256, bE + 512, bE + 768, 64, 128, 128);
    gemm_mfma<false, false, 4, 1, 128><<<dim3(128, 1, 4), blk, 0, stream>>>(
        za, nullptr, B * 128, 3, 128, BIGK, 0, dtflag, WtE, 8192,
        bE, bE + 256, bE + 512, bE + 768, 64,
        zbb, B * 64, 64, stEs, stEq, 64, nullptr, nullptr);

    // ---- Stage F: gating layer c (norm stE + g4/be4) ---------------------
    prep_w<<<dim3(64, 4), blk, 0, stream>>>(
        d_in[22], 4096, d_in[23], 64, stEs, stEq, 64, d_in[12], d_in[13], 63,
        dtflag, WtF, 4096, bF, bF + 256, bF + 512, bF + 768, 64, 64, 64);
    gemm_mfma<false, false, 4, 1, 64><<<dim3(128, 1, 4), blk, 0, stream>>>(
        zbb, nullptr, B * 64, 3, 64, BIGK, 0, dtflag, WtF, 4096,
        bF, bF + 256, bF + 512, bF + 768, 64,
        zc, B * 64, 64, stFs, stFq, 64, nullptr, nullptr);

    // ---- Gate (blocked GEMV, 128 rows/block) -----------------------------
    gate_kernel<<<dim3(B_ROWS / 128, 4), blk, 0, stream>>>(
        zc, stFs, stFq, PF(12), PF(13), PF(24), PF(25), Y0);

    // ---- Stage H: combine, gate weight folded into A-fragments -----------
    gemm_mfma<false, true, 2, 2, 512><<<dim3(256, 2, 4), blk, 0, stream>>>(
        zb, nullptr, 2 * B * 256, 3, 256, 256, B * 256, dtflag, WtH, 131072,
        bH, bH + 1024, bH + 2048, bH + 3072, 256,
        zxc, B * 256, 256, stHs, stHq, 256, partH, Y0);
    reduce_stats<<<dim3(4), blk, 0, stream>>>(partH, 256, 128, stHs, stHq, 1024);

    // ---- Output heads (blocked GEMV, 64 rows/block) ----------------------
    heads_kernel<<<dim3(B_ROWS / 64, 4), blk, 0, stream>>>(
        zxc, stHs, stHq, PF(6), PF(7), PF(28), PF(29), PF(30), PF(31),
        PF(32), PF(33), PF(34), PF(35), d_out, dtflag);
}

// Round 7
// 582.576 us; speedup vs baseline: 1.3628x; 1.3628x over previous
//
#include <hip/hip_runtime.h>
#include <hip/hip_bf16.h>

// ---------------------------------------------------------------------------
// CombineMultiOutputModelWeightedConcat — LDS-staged MFMA pipeline, r7.
// r7 = r5 (best, 584.9us) + block-index remap. r6's REG path REVERTED
// (794us: removing LDS doubled per-wave VMEM instrs and put raw load
// latency in the MFMA dep chain — MfmaUtil fell to 9%).
// Remap: grid linear id re-decomposed with x SLOW -> the 16 (y,inst)
// blocks sharing one 128-row A-panel (stage C) dispatch consecutively,
// turning 2.8x A re-fetch (FETCH 100MB vs 36MB unique) into L3/L2 hits.
// K-loop: r5's single-buffered global_load_lds (XOR-swizzled) + 2
// barriers. Epilogue: r5's LDS-transpose vectorized store (verified).
// Stats: partC/partH partial-write + reduce. gate/heads: blocked GEMV.
// ---------------------------------------------------------------------------

typedef unsigned short u16;
typedef _Float16 f16x8 __attribute__((ext_vector_type(8)));
typedef float f32x4 __attribute__((ext_vector_type(4)));

#define B_ROWS 32768
#define EPS_BN 0.2f
#define BINV (1.0f / 32768.0f)

__device__ __forceinline__ float bf2f(u16 u) {
    union { unsigned int i; float f; } c;
    c.i = ((unsigned int)u) << 16;
    return c.f;
}
__device__ __forceinline__ u16 f2bf(float f) {
    union { float f; unsigned int i; } c;
    c.f = f;
    unsigned int x = c.i;
    return (u16)((x + 0x7FFFu + ((x >> 16) & 1u)) >> 16);
}
__device__ __forceinline__ float h2f(u16 u) {
    _Float16 h;
    __builtin_memcpy(&h, &u, 2);
    return (float)h;
}
__device__ __forceinline__ u16 f2h(float f) {
    _Float16 h = (_Float16)f;
    u16 u;
    __builtin_memcpy(&u, &h, 2);
    return u;
}
__device__ __forceinline__ float ldp(const void* p, long i, int flag) {
    return flag ? bf2f(((const u16*)p)[i]) : ((const float*)p)[i];
}
// async global->LDS, 16B per lane; lds base wave-uniform, lane i lands at +16i
__device__ __forceinline__ void gload16(const u16* gp, u16* lp) {
    __builtin_amdgcn_global_load_lds(
        (const __attribute__((address_space(1))) unsigned int*)gp,
        (__attribute__((address_space(3))) unsigned int*)lp, 16, 0, 0);
}

// --------------------------------------------------------------------------
__global__ void detect_dtype(const u16* __restrict__ x, int* __restrict__ flag) {
    const int lane = threadIdx.x;  // 64 threads
    const u16 v = x[2 * lane];
    const int e = (v >> 7) & 0xFF;
    const bool plausible = (e >= 110 && e <= 140);
    const unsigned long long m = __ballot(plausible);
    if (lane == 0) *flag = (__popcll(m) >= 58) ? 1 : 0;
}

struct PTab { const void* p[20]; int n[20]; int off[20]; };

__global__ void convert_params(PTab t, float* __restrict__ dst,
                               const int* __restrict__ flag) {
    const int ti = blockIdx.y;
    const int n = t.n[ti];
    float* o = dst + t.off[ti];
    const int isbf = *flag;
    for (int i = blockIdx.x * 256 + threadIdx.x; i < n; i += gridDim.x * 256)
        o[i] = ldp(t.p[ti], i, isbf);
}

// ---------------------------------------------------------------------------
// prep_w: Wt[inst][n][k] = f16(s_k * W[k][n]);  T0/T1[n] = sum_{k<,>=khalf}
// t_k*W[k][n];  biasP = bias;  bsum = bias+T0+T1.
// ---------------------------------------------------------------------------
__global__ __launch_bounds__(256) void prep_w(
    const void* __restrict__ W, long wstride,
    const void* __restrict__ bias, long bstride,
    const float* __restrict__ psum, const float* __restrict__ psq, int pstride,
    const void* __restrict__ pg, const void* __restrict__ pbe, int gmask,
    const int* __restrict__ dtflag,
    u16* __restrict__ Wt, long wtstride,
    float* __restrict__ biasP, float* __restrict__ T0o,
    float* __restrict__ T1o, float* __restrict__ bsum, long bost,
    int K, int khalf)
{
    const int tid = threadIdx.x;
    const int n = blockIdx.x;
    const int N = gridDim.x;
    const int inst = blockIdx.y;
    const int flag = *dtflag;
    __shared__ float sn[512], tn[512];
    __shared__ float r0[4], r1[4];

    for (int i = tid; i < K; i += 256) {
        float s = 1.f, t = 0.f;
        if (psum) {
            float m = psum[(long)pstride * inst + i] * BINV;
            float v = psq[(long)pstride * inst + i] * BINV - m * m;
            float g = ldp(pg, i & gmask, flag);
            float b = ldp(pbe, i & gmask, flag);
            s = g * rsqrtf(v + EPS_BN);
            t = b - m * s;
        }
        sn[i] = s; tn[i] = t;
    }
    __syncthreads();
    float p0 = 0.f, p1 = 0.f;
    for (int k = tid; k < K; k += 256) {
        float wv = ldp(W, wstride * inst + (long)k * N + n, flag);
        Wt[wtstride * inst + (long)n * K + k] = f2h(sn[k] * wv);
        float tw = tn[k] * wv;
        if (k < khalf) p0 += tw; else p1 += tw;
    }
#pragma unroll
    for (int off = 32; off; off >>= 1) {
        p0 += __shfl_xor(p0, off);
        p1 += __shfl_xor(p1, off);
    }
    const int lane = tid & 63, wid = tid >> 6;
    if (lane == 0) { r0[wid] = p0; r1[wid] = p1; }
    __syncthreads();
    if (tid == 0) {
        float t0 = r0[0] + r0[1] + r0[2] + r0[3];
        float t1 = r1[0] + r1[1] + r1[2] + r1[3];
        float bp = ldp(bias, bstride * inst + n, flag);
        long o = bost * inst + n;
        biasP[o] = bp; T0o[o] = t0; T1o[o] = t1; bsum[o] = bp + t0 + t1;
    }
}

// ---------------------------------------------------------------------------
// reduce_stats: sum per-block stat partials into stats arrays.
// part layout: [p = inst*gridY + by][x = bx][{sum[colsPer], sq[colsPer]}].
// ---------------------------------------------------------------------------
__global__ __launch_bounds__(256) void reduce_stats(
    const float* __restrict__ part, int X, int colsPer,
    float* __restrict__ outS, float* __restrict__ outQ, int total)
{
    const int t = blockIdx.x * 256 + threadIdx.x;
    if (t >= total) return;
    const int p = t / colsPer, c = t % colsPer;
    const float* pb = part + (long)p * X * 2 * colsPer + c;
    float s = 0.f, q = 0.f;
#pragma unroll 4
    for (int x = 0; x < X; ++x) {
        s += pb[(long)x * 2 * colsPer];
        q += pb[(long)x * 2 * colsPer + colsPer];
    }
    outS[t] = s; outQ[t] = q;
}

// ---------------------------------------------------------------------------
// LDS-staged MFMA GEMM. Block tile (WM*64) x (WN*64), BK=64, 256 threads =
// 4 waves arranged WM x WN (each wave 64x64, 4x4 of 16x16x32, 64 AGPR).
// Block-index REMAP: linear id L re-decomposed with x SLOW so the gy*gz
// blocks sharing one A row-panel dispatch consecutively (A-panel becomes
// an L3/L2 hit for all but the first — kills the 2.8x FETCH amplification).
// LDS layout: tile[r][c] (c = 16B k-chunk) stores global chunk c ^ (r&7);
// staged by global_load_lds (8 rows / inst), read back as ds_read_b128.
// Epilogue: bias/gate + relu + stats, transpose via wave's LDS slice,
// 8 x dwordx4/lane contiguous stores.
// ---------------------------------------------------------------------------
template <bool XSTAGE, bool ROWW, int WM, int WN, int K>
__global__ __launch_bounds__(256, 3) void gemm_mfma(
    const void* __restrict__ X, const void* __restrict__ X2,
    long xstride, int ximask, int ldx, int ksplit, long ksecond,
    const int* __restrict__ dtflag,
    const u16* __restrict__ Wt, long wtstride,
    const float* __restrict__ biasP, const float* __restrict__ T0,
    const float* __restrict__ T1, const float* __restrict__ bsum, int bN,
    u16* __restrict__ Out, long ostride, int ldout,
    float* __restrict__ gsum, float* __restrict__ gsq, int sstride,
    float* __restrict__ part,
    const float* __restrict__ Y0v)
{
    const int tid = threadIdx.x;
    const int lane = tid & 63;
    const int wid = tid >> 6;
    const int wm = wid / WN, wn = wid % WN;

    // ---- block-index remap: x slow, (y,z) fast ----
    const int gx = gridDim.x, gy = gridDim.y;
    const int L = blockIdx.x + gx * (blockIdx.y + gy * blockIdx.z);
    const int grp = gy * gridDim.z;
    const int bx = L / grp;
    const int rem = L % grp;
    const int by = rem % gy;
    const int inst = rem / gy;

    const int rowB = bx * (64 * WM);
    const int nBase = by * (64 * WN);
    const int n0 = nBase + wn * 64;
    const int fm = lane & 15, quad = lane >> 4;

    // LDS: staging (K-loop) / per-wave epilogue transpose tiles
    __shared__ __align__(16) u16 AsBs[(WM + WN) * 4096];
    __shared__ float redS[4][64];
    __shared__ float redQ[4][64];
    u16* As = AsBs;
    u16* Bs = AsBs + WM * 4096;

    bool xf32 = false;
    if constexpr (XSTAGE) xf32 = (*dtflag == 0);
    const char* xb;
    if (XSTAGE) xb = (const char*)(inst == 0 ? X : X2);
    else        xb = (const char*)X + 2l * xstride * (inst & ximask);
    const u16* wtp = Wt + wtstride * inst;
    u16* op = Out + ostride * inst;

    f32x4 acc[4][4];
#pragma unroll
    for (int i = 0; i < 4; ++i)
#pragma unroll
        for (int j = 0; j < 4; ++j) acc[i][j] = (f32x4){0.f, 0.f, 0.f, 0.f};

    _Float16 ysc[2][4];
    if constexpr (ROWW) {
        const float* yp = Y0v + (long)inst * B_ROWS;
#pragma unroll
        for (int mi = 0; mi < 4; ++mi) {
            const float y = yp[rowB + wm * 64 + mi * 16 + fm];
            ysc[0][mi] = (_Float16)y;
            ysc[1][mi] = (_Float16)(1.f - y);
        }
    }

    const int rloc = lane >> 3;            // staging: row within 8-row group
    const int cg = (lane & 7) ^ rloc;      // staging: swizzled global chunk

    for (int kt = 0; kt < K / 64; ++kt) {
        const int kk = kt * 64;
        __syncthreads();
        // ---- stage A tile ----
        if constexpr (XSTAGE) {
            // VALU convert path (fp32 or bf16 -> fp16), same swizzled layout
#pragma unroll
            for (int p = 0; p < WM * 2; ++p) {
                const int s = p * 256 + tid;       // chunk id
                const int m = s >> 3, c = s & 7;
                const int g = c ^ (m & 7);
                f16x8 h;
                if (xf32) {
                    const float* gp = (const float*)xb + (long)(rowB + m) * ldx + kk + g * 8;
                    const float4 u = *(const float4*)gp;
                    const float4 u2 = *(const float4*)(gp + 4);
                    h[0] = (_Float16)u.x;  h[1] = (_Float16)u.y;
                    h[2] = (_Float16)u.z;  h[3] = (_Float16)u.w;
                    h[4] = (_Float16)u2.x; h[5] = (_Float16)u2.y;
                    h[6] = (_Float16)u2.z; h[7] = (_Float16)u2.w;
                } else {
                    const uint4 v = *(const uint4*)((const u16*)xb + (long)(rowB + m) * ldx + kk + g * 8);
                    const u16* pv = (const u16*)&v;
#pragma unroll
                    for (int j = 0; j < 8; ++j) h[j] = (_Float16)bf2f(pv[j]);
                }
                *(f16x8*)&As[s * 8] = h;
            }
        } else {
            const u16* xs = (const u16*)xb;
            int kkr = kk;
            if (kk >= ksplit) { xs += ksecond; kkr -= ksplit; }
#pragma unroll
            for (int s = wid; s < WM * 8; s += 4)
                gload16(xs + (long)(rowB + s * 8 + rloc) * ldx + kkr + cg * 8,
                        &As[s * 512 + lane * 8]);
        }
        // ---- stage B tile ----
#pragma unroll
        for (int s = wid; s < WN * 8; s += 4)
            gload16(wtp + (long)(nBase + s * 8 + rloc) * K + kk + cg * 8,
                    &Bs[s * 512 + lane * 8]);
        __syncthreads();

        // ---- compute ----
        const int sel = (ROWW && kk >= ksplit) ? 1 : 0;
#pragma unroll
        for (int q = 0; q < 2; ++q) {
            f16x8 af[4], bfr[4];
#pragma unroll
            for (int mi = 0; mi < 4; ++mi) {
                const int mm = wm * 64 + mi * 16 + fm;
                af[mi] = *(const f16x8*)&As[mm * 64 + (((q * 4 + quad) ^ (mm & 7)) * 8)];
            }
            if constexpr (ROWW) {
#pragma unroll
                for (int mi = 0; mi < 4; ++mi) {
                    const _Float16 yh = ysc[sel][mi];
#pragma unroll
                    for (int j = 0; j < 8; ++j) af[mi][j] *= yh;
                }
            }
#pragma unroll
            for (int ni = 0; ni < 4; ++ni) {
                const int nn = wn * 64 + ni * 16 + fm;
                bfr[ni] = *(const f16x8*)&Bs[nn * 64 + (((q * 4 + quad) ^ (nn & 7)) * 8)];
            }
#pragma unroll
            for (int mi = 0; mi < 4; ++mi)
#pragma unroll
                for (int ni = 0; ni < 4; ++ni)
                    acc[mi][ni] = __builtin_amdgcn_mfma_f32_16x16x32_f16(
                        af[mi], bfr[ni], acc[mi][ni], 0, 0, 0);
        }
    }

    __syncthreads();   // K-loop LDS dead from here; reuse as epilogue tiles

    // ---- epilogue phase 1: bias/relu/stats + transpose into wave's LDS ----
    // wave tile: u16[64][64], chunk-swizzled col ^= ((row>>1)&7)<<3
    u16* wtile = AsBs + wid * 4096;
    const int R0 = rowB + wm * 64;

    float yv[16];
    if constexpr (ROWW) {
        const float* yp = Y0v + (long)inst * B_ROWS;
#pragma unroll
        for (int mi = 0; mi < 4; ++mi)
#pragma unroll
            for (int r = 0; r < 4; ++r)
                yv[mi * 4 + r] = yp[R0 + mi * 16 + quad * 4 + r];
    }

#pragma unroll
    for (int ni = 0; ni < 4; ++ni) {
        const int nc = ni * 16 + fm;
        const int n = n0 + nc;
        float bS = 0.f, bP = 0.f, t0v = 0.f, t1v = 0.f;
        if constexpr (ROWW) {
            bP = biasP[(long)inst * bN + n];
            t0v = T0[(long)inst * bN + n];
            t1v = T1[(long)inst * bN + n];
        } else {
            bS = bsum[(long)inst * bN + n];
        }
        float s = 0.f, qq = 0.f;
#pragma unroll
        for (int mi = 0; mi < 4; ++mi) {
#pragma unroll
            for (int r = 0; r < 4; ++r) {
                float v;
                if constexpr (ROWW) {
                    const float y = yv[mi * 4 + r];
                    v = acc[mi][ni][r] + y * t0v + (1.f - y) * t1v + bP;
                } else {
                    v = acc[mi][ni][r] + bS;
                }
                v = fmaxf(v, 0.f);
                s += v; qq += v * v;
                const int lr = mi * 16 + quad * 4 + r;
                wtile[lr * 64 + (nc ^ (((lr >> 1) & 7) << 3))] = f2h(v);
            }
        }
        s += __shfl_xor(s, 16);  s += __shfl_xor(s, 32);
        qq += __shfl_xor(qq, 16); qq += __shfl_xor(qq, 32);
        if (quad == 0) { redS[wid][nc] = s; redQ[wid][nc] = qq; }
    }

    // ---- epilogue phase 2: coalesced 16B/lane stores from LDS ----
    {
        const int l8 = lane & 7, r8 = lane >> 3;
#pragma unroll
        for (int it = 0; it < 8; ++it) {
            const int lr = it * 8 + r8;
            const int ch = l8 ^ ((lr >> 1) & 7);
            const f16x8 hv = *(const f16x8*)&wtile[lr * 64 + ch * 8];
            *(f16x8*)(op + (long)(R0 + lr) * ldout + n0 + l8 * 8) = hv;
        }
    }

    __syncthreads();
    if (tid < WN * 64) {
        const int wnc = tid >> 6, within = tid & 63;
        float s = 0.f, q = 0.f;
#pragma unroll
        for (int w = 0; w < WM; ++w) {
            s += redS[w * WN + wnc][within];
            q += redQ[w * WN + wnc][within];
        }
        if (part) {
            // per-block partial (coalesced, no atomics); reduce_stats sums.
            float* pb = part +
                (long)((inst * gridDim.y + by) * gridDim.x + bx)
                    * (2 * WN * 64);
            pb[tid] = s;
            pb[WN * 64 + tid] = q;
        } else {
            atomicAdd(&gsum[(long)inst * sstride + nBase + tid], s);
            atomicAdd(&gsq [(long)inst * sstride + nBase + tid], q);
        }
    }
}

// ---------------------------------------------------------------------------
// gate_kernel: blocked GEMV, BN folded into LDS-resident scaled weights.
// Block = 256 threads = 128 rows x 2 col-segments (32 cols each).
// ---------------------------------------------------------------------------
__global__ __launch_bounds__(256) void gate_kernel(
    const u16* __restrict__ zc,
    const float* __restrict__ stFs, const float* __restrict__ stFq,
    const float* __restrict__ g4, const float* __restrict__ be4,
    const float* __restrict__ Wy, const float* __restrict__ by,
    float* __restrict__ Y0)
{
    const int tid = threadIdx.x;
    const int k = blockIdx.y;
    const int r0 = blockIdx.x * 128;

    __shared__ __align__(8) float Ws2[64][2];
    __shared__ float cg[2];

    // ---- fold BN into weights (one column per lane, first wave) ----
    if (tid < 64) {
        const int c = tid;
        const float m = stFs[k * 64 + c] * BINV;
        const float v = stFq[k * 64 + c] * BINV - m * m;
        const float s = g4[c] * rsqrtf(v + EPS_BN);
        const float t = be4[c] - m * s;
        const float w0 = Wy[k * 128 + c * 2 + 0];
        const float w1 = Wy[k * 128 + c * 2 + 1];
        Ws2[c][0] = s * w0;
        Ws2[c][1] = s * w1;
        float t0 = t * w0, t1 = t * w1;
#pragma unroll
        for (int off = 32; off; off >>= 1) {
            t0 += __shfl_xor(t0, off);
            t1 += __shfl_xor(t1, off);
        }
        if (c == 0) {
            cg[0] = t0 + by[k * 2 + 0];
            cg[1] = t1 + by[k * 2 + 1];
        }
    }
    __syncthreads();

    // ---- GEMV: 1 row / 2 threads, 32 columns each ----
    const int row = r0 + (tid >> 1);
    const int seg = tid & 1;
    const u16* xp = zc + ((long)k * B_ROWS + row) * 64 + seg * 32;
    float a0 = 0.f, a1 = 0.f;
#pragma unroll
    for (int it = 0; it < 4; ++it) {
        const uint4 v = *(const uint4*)(xp + it * 8);
        const u16* pv = (const u16*)&v;
#pragma unroll
        for (int e = 0; e < 8; ++e) {
            const int c = seg * 32 + it * 8 + e;
            const float x = h2f(pv[e]);
            a0 += x * Ws2[c][0];
            a1 += x * Ws2[c][1];
        }
    }
    a0 += __shfl_xor(a0, 1);
    a1 += __shfl_xor(a1, 1);
    if (seg == 0) {
        const float l0 = a0 + cg[0];
        const float l1 = a1 + cg[1];
        Y0[(long)k * B_ROWS + row] = 1.f / (1.f + __expf(l1 - l0));
    }
}

// ---------------------------------------------------------------------------
// heads_kernel: blocked GEMV, BN folded into LDS weight table Ws[256][8]
// (fp32, XOR-swizzled row index so 4 concurrent col-segments hit distinct
// bank groups). Block = 256 threads = 64 rows x 4 segments (64 cols).
// ---------------------------------------------------------------------------
__global__ __launch_bounds__(256) void heads_kernel(
    const u16* __restrict__ zxc,
    const float* __restrict__ stHs, const float* __restrict__ stHq,
    const float* __restrict__ g1, const float* __restrict__ be1,
    const float* __restrict__ Wo1, const float* __restrict__ bo1,
    const float* __restrict__ Wo2, const float* __restrict__ bo2,
    const float* __restrict__ Wo3, const float* __restrict__ bo3,
    const float* __restrict__ Wo4, const float* __restrict__ bo4,
    void* __restrict__ out, const int* __restrict__ dtflag)
{
    const int tid = threadIdx.x;
    const int k = blockIdx.y;
    const int r0 = blockIdx.x * 64;

    const float* Wo; const float* bo; int nk; long obase;
    if (k == 0)      { Wo = Wo1; bo = bo1; nk = 3; obase = 0; }
    else if (k == 1) { Wo = Wo2; bo = bo2; nk = 3; obase = (long)3 * B_ROWS; }
    else if (k == 2) { Wo = Wo3; bo = bo3; nk = 6; obase = (long)6 * B_ROWS; }
    else             { Wo = Wo4; bo = bo4; nk = 4; obase = (long)12 * B_ROWS; }

    __shared__ __align__(16) float Ws[256][8];
    __shared__ float cj[8];
    __shared__ float redC[4][8];

    // ---- fold BN into weights (one column per thread) ----
    {
        const int c = tid;
        const float m = stHs[k * 256 + c] * BINV;
        const float v = stHq[k * 256 + c] * BINV - m * m;
        const float s = g1[c] * rsqrtf(v + EPS_BN);
        const float t = be1[c] - m * s;
        const int rs = c ^ (c >> 6);       // bank-group swizzle
        float tw[6];
#pragma unroll
        for (int j = 0; j < 6; ++j) {
            const float w = (j < nk) ? Wo[c * nk + j] : 0.f;
            Ws[rs][j] = s * w;
            tw[j] = t * w;
        }
        Ws[rs][6] = 0.f; Ws[rs][7] = 0.f;
#pragma unroll
        for (int off = 32; off; off >>= 1)
#pragma unroll
            for (int j = 0; j < 6; ++j) tw[j] += __shfl_xor(tw[j], off);
        const int lane = tid & 63, wid = tid >> 6;
        if (lane < 6) redC[wid][lane] = tw[lane];
    }
    __syncthreads();
    if (tid < 8) {
        float s4 = 0.f;
        if (tid < 6) s4 = redC[0][tid] + redC[1][tid] + redC[2][tid] + redC[3][tid];
        cj[tid] = (tid < nk) ? s4 + bo[tid] : 0.f;
    }
    __syncthreads();

    // ---- GEMV: 1 row / 4 threads, 64 columns each ----
    const int row = r0 + (tid >> 2);
    const int seg = tid & 3;
    const u16* xp = zxc + ((long)k * B_ROWS + row) * 256 + seg * 64;
    float acc[6];
#pragma unroll
    for (int j = 0; j < 6; ++j) acc[j] = 0.f;
#pragma unroll
    for (int it = 0; it < 8; ++it) {
        const uint4 v = *(const uint4*)(xp + it * 8);
        const u16* pv = (const u16*)&v;
#pragma unroll
        for (int e = 0; e < 8; ++e) {
            const int cc = it * 8 + e;             // column within segment
            const int rs = (seg * 64 + cc) ^ seg;  // swizzled LDS row
            const float x = h2f(pv[e]);
            const f32x4 w0 = *(const f32x4*)&Ws[rs][0];
            const f32x4 w1 = *(const f32x4*)&Ws[rs][4];
            acc[0] += x * w0[0];
            acc[1] += x * w0[1];
            acc[2] += x * w0[2];
            acc[3] += x * w0[3];
            acc[4] += x * w1[0];
            acc[5] += x * w1[1];
        }
    }
#pragma unroll
    for (int j = 0; j < 6; ++j) {
        acc[j] += __shfl_xor(acc[j], 1);
        acc[j] += __shfl_xor(acc[j], 2);
    }

    if (seg == 0) {
        float l[6];
        float mx = -1e30f;
#pragma unroll
        for (int j = 0; j < 6; j++)
            if (j < nk) { l[j] = acc[j] + cj[j]; mx = fmaxf(mx, l[j]); }
        float e[6];
        float se = 0.f;
#pragma unroll
        for (int j = 0; j < 6; j++)
            if (j < nk) { e[j] = __expf(l[j] - mx); se += e[j]; }
        const float inv = 1.f / se;
        if (*dtflag) {
            u16* ob = (u16*)out;
#pragma unroll
            for (int j = 0; j < 6; j++)
                if (j < nk) ob[obase + (long)row * nk + j] = f2bf(e[j] * inv);
        } else {
            float* of = (float*)out;
#pragma unroll
            for (int j = 0; j < 6; j++)
                if (j < nk) of[obase + (long)row * nk + j] = e[j] * inv;
        }
    }
}

__global__ void fill_sentinel(u16* out, int n) {
    int i = blockIdx.x * 256 + threadIdx.x;
    if (i < n) out[i] = 0x3E80;
}

// ---------------------------------------------------------------------------
extern "C" void kernel_launch(void* const* d_in, const int* in_sizes, int n_in,
                              void* d_out, int out_size, void* d_ws, size_t ws_size,
                              hipStream_t stream)
{
    const long B = B_ROWS;
    char* ws = (char*)d_ws;
    const size_t MB = 1024 * 1024;

    // Lifetime-aliased activation layout (fp16)
    u16* z1  = (u16*)(ws);                      // [2][B][256]  (0..32MB)
    u16* z2  = (u16*)(ws + 32 * MB);            // [2][B][256]  (32..64MB)
    u16* za  = (u16*)(ws);                      // [4][B][128]  (0..32MB)
    u16* zbb = (u16*)(ws + 32 * MB);            // [4][B][64]   (32..48MB)
    u16* zc  = (u16*)(ws + 48 * MB);            // [4][B][64]   (48..64MB)
    u16* zxc = (u16*)(ws);                      // [4][B][256]  (0..64MB!)
    u16* zb  = (u16*)(ws + 64 * MB);            // [k][s][B][256] (64..192MB)
    float* Y0 = (float*)(ws + 192 * MB);                   // 512 KB
    float* stats = (float*)(ws + 192 * MB + 512 * 1024);   // 40 KB
    int* dtflag = (int*)(ws + 192 * MB + 576 * 1024);
    float* Pst = (float*)(ws + 192 * MB + 640 * 1024);     // small fp32 params

    // Wt region (fp16, prescaled+transposed weights)
    u16* WtA = (u16*)(ws + 193 * MB);                 // [256][512]     (+0..256KB)
    u16* WtB = WtA + 131072;                          // [2][256][256]  (+256..512KB)
    u16* WtC = WtB + 131072;                          // [8][256][256]  (+512KB..1.5MB)
    u16* WtD = WtC + 524288;                          // [4][128][512]  (+1.5..2MB)
    u16* WtH = WtD + 262144;                          // [4][256][512]  (+2..3MB)
    u16* WtE = WtH + 524288;                          // [4][64][128]
    u16* WtF = WtE + 32768;                           // [4][64][64]
    float* biasArea = (float*)(ws + 197 * MB);
    float* bA = biasArea;        // 2048
    float* bB = bA + 2048;       // 2048
    float* bC = bB + 2048;       // 8192
    float* bD = bC + 8192;       // 2048
    float* bH = bD + 2048;       // 4096
    float* bE = bH + 4096;       // 1024
    float* bF = bE + 1024;       // 1024

    // Stat-partial scratch in lifetime-dead regions:
    //  stage C partials: 4MB at ws+0 (z1 dead after B; za written at D,
    //    after reduce_stats(C)).  SAFE.
    //  stage H partials: 2MB at ws+193MB = WtA..WtD, all dead by stage H.
    float* partC = (float*)(ws);
    float* partH = (float*)(ws + 193 * MB);

    // fp32 param staging (gate/heads consumers)
    const int cIdx[20] = {6,7,10,11,12,13,20,21,22,23,24,25,28,29,30,31,32,33,34,35};
    PTab tab;
    int mapOff[36];
    int acc = 0;
    for (int i = 0; i < 20; i++) {
        tab.p[i] = d_in[cIdx[i]];
        tab.n[i] = in_sizes[cIdx[i]];
        tab.off[i] = acc;
        mapOff[cIdx[i]] = acc;
        acc += in_sizes[cIdx[i]];
    }
    const size_t need = 197 * MB + 20480 * 4 + 4096;
    if (need > ws_size || (size_t)acc * 4 > 384 * 1024) {
        fill_sentinel<<<(out_size + 255) / 256, 256, 0, stream>>>((u16*)d_out, out_size);
        return;
    }
    auto PF = [&](int idx) { return Pst + mapOff[idx]; };

    float* stAs = stats;        float* stAq = stAs + 512;   // [2][256]
    float* stBs = stAq + 512;   float* stBq = stBs + 512;   // [2][256]
    float* stCs = stBq + 512;   float* stCq = stCs + 2048;  // [k][s][256]
    float* stDs = stCq + 2048;  float* stDq = stDs + 512;   // [4][128]
    float* stEs = stDq + 512;   float* stEq = stEs + 256;   // [4][64]
    float* stFs = stEq + 256;   float* stFq = stFs + 256;   // [4][64]
    float* stHs = stFq + 256;   float* stHq = stHs + 1024;  // [4][256]

    hipMemsetAsync(stats, 0, 10240 * 4, stream);
    detect_dtype<<<1, 64, 0, stream>>>((const u16*)d_in[0], dtflag);
    convert_params<<<dim3(32, 20), 256, 0, stream>>>(tab, Pst, dtflag);

    const dim3 blk(256);
    const int BIGK = 1 << 29;  // "never split"

    // ---- Stage A: trunk L1 (dual-dtype X, VALU staging) ------------------
    prep_w<<<dim3(256, 2), blk, 0, stream>>>(
        d_in[2], 0, d_in[3], 0, nullptr, nullptr, 0, nullptr, nullptr, 0,
        dtflag, WtA, 0, bA, bA + 512, bA + 1024, bA + 1536, 256, 512, 512);
    gemm_mfma<true, false, 2, 2, 512><<<dim3(256, 2, 2), blk, 0, stream>>>(
        d_in[0], d_in[1], 0, 0, 512, BIGK, 0, dtflag, WtA, 0,
        bA, bA + 512, bA + 1024, bA + 1536, 256,
        z1, B * 256, 256, stAs, stAq, 256, nullptr, nullptr);

    // ---- Stage B: trunk L2 (norm stA + g1/be1 folded into WtB) -----------
    prep_w<<<dim3(256, 2), blk, 0, stream>>>(
        d_in[4], 0, d_in[5], 0, stAs, stAq, 256, d_in[6], d_in[7], 255,
        dtflag, WtB, 65536, bB, bB + 512, bB + 1024, bB + 1536, 256, 256, 256);
    gemm_mfma<false, false, 2, 2, 256><<<dim3(256, 2, 2), blk, 0, stream>>>(
        z1, nullptr, B * 256, 3, 256, BIGK, 0, dtflag, WtB, 65536,
        bB, bB + 512, bB + 1024, bB + 1536, 256,
        z2, B * 256, 256, stBs, stBq, 256, nullptr, nullptr);

    // ---- Stage C: 8 branch projections (norm stB + g2/be2) ---------------
    for (int s = 0; s < 2; s++) {
        prep_w<<<dim3(256, 4), blk, 0, stream>>>(
            d_in[s ? 16 : 14], 65536, d_in[s ? 17 : 15], 256,
            stBs + s * 256, stBq + s * 256, 0, d_in[8], d_in[9], 255,
            dtflag, WtC + s * 65536, 131072,
            bC + s * 256, bC + 2048 + s * 256, bC + 4096 + s * 256,
            bC + 6144 + s * 256, 512, 256, 256);
    }
    gemm_mfma<false, false, 2, 2, 256><<<dim3(256, 2, 8), blk, 0, stream>>>(
        z2, nullptr, B * 256, 1, 256, BIGK, 0, dtflag, WtC, 65536,
        bC, bC + 2048, bC + 4096, bC + 6144, 256,
        zb, B * 256, 256, stCs, stCq, 256, partC, nullptr);
    reduce_stats<<<dim3(8), blk, 0, stream>>>(partC, 256, 128, stCs, stCq, 2048);

    // ---- Stage D prep+gemm, H prep (stC available) -----------------------
    prep_w<<<dim3(128, 4), blk, 0, stream>>>(
        d_in[18], 65536, d_in[19], 128, stCs, stCq, 512, d_in[6], d_in[7], 255,
        dtflag, WtD, 65536, bD, bD + 512, bD + 1024, bD + 1536, 128, 512, 512);
    prep_w<<<dim3(256, 4), blk, 0, stream>>>(
        d_in[26], 131072, d_in[27], 256, stCs, stCq, 512, d_in[6], d_in[7], 255,
        dtflag, WtH, 131072, bH, bH + 1024, bH + 2048, bH + 3072, 256, 512, 256);
    gemm_mfma<false, false, 2, 2, 512><<<dim3(256, 1, 4), blk, 0, stream>>>(
        zb, nullptr, 2 * B * 256, 3, 256, 256, B * 256, dtflag, WtD, 65536,
        bD, bD + 512, bD + 1024, bD + 1536, 128,
        za, B * 128, 128, stDs, stDq, 128, nullptr, nullptr);

    // ---- Stage E: gating layer b (norm stD + g3/be3) ---------------------
    prep_w<<<dim3(64, 4), blk, 0, stream>>>(
        d_in[20], 8192, d_in[21], 64, stDs, stDq, 128, d_in[10], d_in[11], 127,
        dtflag, WtE, 8192, bE, bE + 256, bE + 512, bE + 768, 64, 128, 128);
    gemm_mfma<false, false, 4, 1, 128><<<dim3(128, 1, 4), blk, 0, stream>>>(
        za, nullptr, B * 128, 3, 128, BIGK, 0, dtflag, WtE, 8192,
        bE, bE + 256, bE + 512, bE + 768, 64,
        zbb, B * 64, 64, stEs, stEq, 64, nullptr, nullptr);

    // ---- Stage F: gating layer c (norm stE + g4/be4) ---------------------
    prep_w<<<dim3(64, 4), blk, 0, stream>>>(
        d_in[22], 4096, d_in[23], 64, stEs, stEq, 64, d_in[12], d_in[13], 63,
        dtflag, WtF, 4096, bF, bF + 256, bF + 512, bF + 768, 64, 64, 64);
    gemm_mfma<false, false, 4, 1, 64><<<dim3(128, 1, 4), blk, 0, stream>>>(
        zbb, nullptr, B * 64, 3, 64, BIGK, 0, dtflag, WtF, 4096,
        bF, bF + 256, bF + 512, bF + 768, 64,
        zc, B * 64, 64, stFs, stFq, 64, nullptr, nullptr);

    // ---- Gate (blocked GEMV, 128 rows/block) -----------------------------
    gate_kernel<<<dim3(B_ROWS / 128, 4), blk, 0, stream>>>(
        zc, stFs, stFq, PF(12), PF(13), PF(24), PF(25), Y0);

    // ---- Stage H: combine, gate weight folded into A-fragments -----------
    gemm_mfma<false, true, 2, 2, 512><<<dim3(256, 2, 4), blk, 0, stream>>>(
        zb, nullptr, 2 * B * 256, 3, 256, 256, B * 256, dtflag, WtH, 131072,
        bH, bH + 1024, bH + 2048, bH + 3072, 256,
        zxc, B * 256, 256, stHs, stHq, 256, partH, Y0);
    reduce_stats<<<dim3(4), blk, 0, stream>>>(partH, 256, 128, stHs, stHq, 1024);

    // ---- Output heads (blocked GEMV, 64 rows/block) ----------------------
    heads_kernel<<<dim3(B_ROWS / 64, 4), blk, 0, stream>>>(
        zxc, stHs, stHq, PF(6), PF(7), PF(28), PF(29), PF(30), PF(31),
        PF(32), PF(33), PF(34), PF(35), d_out, dtflag);
}

// Round 9
// 569.838 us; speedup vs baseline: 1.3933x; 1.0224x over previous
//
#include <hip/hip_runtime.h>
#include <hip/hip_bf16.h>

// ---------------------------------------------------------------------------
// CombineMultiOutputModelWeightedConcat — LDS-staged MFMA pipeline, r9.
// r9 = r8 resubmitted verbatim (r8 bench was an infra failure: "container
// failed twice" — no signal). Per-stage block-remap modes + XCD chunking.
// r7 lesson: x-slow remap helped stage C (A shared across 8 insts) but
// REGRESSED stage D 86->91us, FETCH 100->132MB (D's A-source is per-inst:
// grouping interleaved 4 unrelated 32MB streams). Also consecutive linear
// ids round-robin across 8 XCDs (private L2s) so r7's "consecutive sharers"
// only shared via L3. Now: lid = (L%8)*(NB/8)+L/8 (XCD chunking — in-chunk
// neighbors land on the SAME private L2), then per-stage RMODE:
//   0 = bx-fast streaming (D,E,F: per-inst A, no sharing)
//   1 = bx-slow full (y,inst) grouping (C: 8 insts share 2 A-sources)
//   2 = by-fast, inst slowest (A,B,H: sharing only across y)
// K-loop: single-buffered global_load_lds (XOR-swizzled) + 2 barriers.
// Epilogue: LDS-transpose vectorized store. Stats: partC/partH + reduce.
// ---------------------------------------------------------------------------

typedef unsigned short u16;
typedef _Float16 f16x8 __attribute__((ext_vector_type(8)));
typedef float f32x4 __attribute__((ext_vector_type(4)));

#define B_ROWS 32768
#define EPS_BN 0.2f
#define BINV (1.0f / 32768.0f)

__device__ __forceinline__ float bf2f(u16 u) {
    union { unsigned int i; float f; } c;
    c.i = ((unsigned int)u) << 16;
    return c.f;
}
__device__ __forceinline__ u16 f2bf(float f) {
    union { float f; unsigned int i; } c;
    c.f = f;
    unsigned int x = c.i;
    return (u16)((x + 0x7FFFu + ((x >> 16) & 1u)) >> 16);
}
__device__ __forceinline__ float h2f(u16 u) {
    _Float16 h;
    __builtin_memcpy(&h, &u, 2);
    return (float)h;
}
__device__ __forceinline__ u16 f2h(float f) {
    _Float16 h = (_Float16)f;
    u16 u;
    __builtin_memcpy(&u, &h, 2);
    return u;
}
__device__ __forceinline__ float ldp(const void* p, long i, int flag) {
    return flag ? bf2f(((const u16*)p)[i]) : ((const float*)p)[i];
}
// async global->LDS, 16B per lane; lds base wave-uniform, lane i lands at +16i
__device__ __forceinline__ void gload16(const u16* gp, u16* lp) {
    __builtin_amdgcn_global_load_lds(
        (const __attribute__((address_space(1))) unsigned int*)gp,
        (__attribute__((address_space(3))) unsigned int*)lp, 16, 0, 0);
}

// --------------------------------------------------------------------------
__global__ void detect_dtype(const u16* __restrict__ x, int* __restrict__ flag) {
    const int lane = threadIdx.x;  // 64 threads
    const u16 v = x[2 * lane];
    const int e = (v >> 7) & 0xFF;
    const bool plausible = (e >= 110 && e <= 140);
    const unsigned long long m = __ballot(plausible);
    if (lane == 0) *flag = (__popcll(m) >= 58) ? 1 : 0;
}

struct PTab { const void* p[20]; int n[20]; int off[20]; };

__global__ void convert_params(PTab t, float* __restrict__ dst,
                               const int* __restrict__ flag) {
    const int ti = blockIdx.y;
    const int n = t.n[ti];
    float* o = dst + t.off[ti];
    const int isbf = *flag;
    for (int i = blockIdx.x * 256 + threadIdx.x; i < n; i += gridDim.x * 256)
        o[i] = ldp(t.p[ti], i, isbf);
}

// ---------------------------------------------------------------------------
// prep_w: Wt[inst][n][k] = f16(s_k * W[k][n]);  T0/T1[n] = sum_{k<,>=khalf}
// t_k*W[k][n];  biasP = bias;  bsum = bias+T0+T1.
// ---------------------------------------------------------------------------
__global__ __launch_bounds__(256) void prep_w(
    const void* __restrict__ W, long wstride,
    const void* __restrict__ bias, long bstride,
    const float* __restrict__ psum, const float* __restrict__ psq, int pstride,
    const void* __restrict__ pg, const void* __restrict__ pbe, int gmask,
    const int* __restrict__ dtflag,
    u16* __restrict__ Wt, long wtstride,
    float* __restrict__ biasP, float* __restrict__ T0o,
    float* __restrict__ T1o, float* __restrict__ bsum, long bost,
    int K, int khalf)
{
    const int tid = threadIdx.x;
    const int n = blockIdx.x;
    const int N = gridDim.x;
    const int inst = blockIdx.y;
    const int flag = *dtflag;
    __shared__ float sn[512], tn[512];
    __shared__ float r0[4], r1[4];

    for (int i = tid; i < K; i += 256) {
        float s = 1.f, t = 0.f;
        if (psum) {
            float m = psum[(long)pstride * inst + i] * BINV;
            float v = psq[(long)pstride * inst + i] * BINV - m * m;
            float g = ldp(pg, i & gmask, flag);
            float b = ldp(pbe, i & gmask, flag);
            s = g * rsqrtf(v + EPS_BN);
            t = b - m * s;
        }
        sn[i] = s; tn[i] = t;
    }
    __syncthreads();
    float p0 = 0.f, p1 = 0.f;
    for (int k = tid; k < K; k += 256) {
        float wv = ldp(W, wstride * inst + (long)k * N + n, flag);
        Wt[wtstride * inst + (long)n * K + k] = f2h(sn[k] * wv);
        float tw = tn[k] * wv;
        if (k < khalf) p0 += tw; else p1 += tw;
    }
#pragma unroll
    for (int off = 32; off; off >>= 1) {
        p0 += __shfl_xor(p0, off);
        p1 += __shfl_xor(p1, off);
    }
    const int lane = tid & 63, wid = tid >> 6;
    if (lane == 0) { r0[wid] = p0; r1[wid] = p1; }
    __syncthreads();
    if (tid == 0) {
        float t0 = r0[0] + r0[1] + r0[2] + r0[3];
        float t1 = r1[0] + r1[1] + r1[2] + r1[3];
        float bp = ldp(bias, bstride * inst + n, flag);
        long o = bost * inst + n;
        biasP[o] = bp; T0o[o] = t0; T1o[o] = t1; bsum[o] = bp + t0 + t1;
    }
}

// ---------------------------------------------------------------------------
// reduce_stats: sum per-block stat partials into stats arrays.
// part layout: [p = inst*gridY + by][x = bx][{sum[colsPer], sq[colsPer]}].
// ---------------------------------------------------------------------------
__global__ __launch_bounds__(256) void reduce_stats(
    const float* __restrict__ part, int X, int colsPer,
    float* __restrict__ outS, float* __restrict__ outQ, int total)
{
    const int t = blockIdx.x * 256 + threadIdx.x;
    if (t >= total) return;
    const int p = t / colsPer, c = t % colsPer;
    const float* pb = part + (long)p * X * 2 * colsPer + c;
    float s = 0.f, q = 0.f;
#pragma unroll 4
    for (int x = 0; x < X; ++x) {
        s += pb[(long)x * 2 * colsPer];
        q += pb[(long)x * 2 * colsPer + colsPer];
    }
    outS[t] = s; outQ[t] = q;
}

// ---------------------------------------------------------------------------
// LDS-staged MFMA GEMM. Block tile (WM*64) x (WN*64), BK=64, 256 threads =
// 4 waves arranged WM x WN (each wave 64x64, 4x4 of 16x16x32, 64 AGPR).
// Block-index remap: XCD chunking (lid = (L%8)*(NB/8)+L/8) so in-chunk
// neighbors share one private L2, then RMODE decomposition:
//   0: bx fast (streaming)  1: bx slow, (y,inst) fast  2: by fast, inst slow
// LDS layout: tile[r][c] stores global chunk c ^ (r&7); staged by
// global_load_lds, read back as ds_read_b128. Epilogue: bias/gate + relu +
// stats, transpose via wave's LDS slice, 8 x dwordx4/lane stores.
// ---------------------------------------------------------------------------
template <bool XSTAGE, bool ROWW, int WM, int WN, int K, int RMODE>
__global__ __launch_bounds__(256, 3) void gemm_mfma(
    const void* __restrict__ X, const void* __restrict__ X2,
    long xstride, int ximask, int ldx, int ksplit, long ksecond,
    const int* __restrict__ dtflag,
    const u16* __restrict__ Wt, long wtstride,
    const float* __restrict__ biasP, const float* __restrict__ T0,
    const float* __restrict__ T1, const float* __restrict__ bsum, int bN,
    u16* __restrict__ Out, long ostride, int ldout,
    float* __restrict__ gsum, float* __restrict__ gsq, int sstride,
    float* __restrict__ part,
    const float* __restrict__ Y0v)
{
    const int tid = threadIdx.x;
    const int lane = tid & 63;
    const int wid = tid >> 6;
    const int wm = wid / WN, wn = wid % WN;

    // ---- block-index remap ----
    const int gx = gridDim.x, gy = gridDim.y;
    const int NB = gx * gy * gridDim.z;
    const int L = blockIdx.x + gx * (blockIdx.y + gy * blockIdx.z);
    const int lid = (NB % 8 == 0) ? (L % 8) * (NB / 8) + L / 8 : L;
    int bx, by, inst;
    if constexpr (RMODE == 0) {
        bx = lid % gx; const int r = lid / gx; by = r % gy; inst = r / gy;
    } else if constexpr (RMODE == 1) {
        const int grp = gy * gridDim.z;
        bx = lid / grp; const int r = lid % grp; by = r % gy; inst = r / gy;
    } else {
        by = lid % gy; const int r = lid / gy; bx = r % gx; inst = r / gx;
    }

    const int rowB = bx * (64 * WM);
    const int nBase = by * (64 * WN);
    const int n0 = nBase + wn * 64;
    const int fm = lane & 15, quad = lane >> 4;

    // LDS: staging (K-loop) / per-wave epilogue transpose tiles
    __shared__ __align__(16) u16 AsBs[(WM + WN) * 4096];
    __shared__ float redS[4][64];
    __shared__ float redQ[4][64];
    u16* As = AsBs;
    u16* Bs = AsBs + WM * 4096;

    bool xf32 = false;
    if constexpr (XSTAGE) xf32 = (*dtflag == 0);
    const char* xb;
    if (XSTAGE) xb = (const char*)(inst == 0 ? X : X2);
    else        xb = (const char*)X + 2l * xstride * (inst & ximask);
    const u16* wtp = Wt + wtstride * inst;
    u16* op = Out + ostride * inst;

    f32x4 acc[4][4];
#pragma unroll
    for (int i = 0; i < 4; ++i)
#pragma unroll
        for (int j = 0; j < 4; ++j) acc[i][j] = (f32x4){0.f, 0.f, 0.f, 0.f};

    _Float16 ysc[2][4];
    if constexpr (ROWW) {
        const float* yp = Y0v + (long)inst * B_ROWS;
#pragma unroll
        for (int mi = 0; mi < 4; ++mi) {
            const float y = yp[rowB + wm * 64 + mi * 16 + fm];
            ysc[0][mi] = (_Float16)y;
            ysc[1][mi] = (_Float16)(1.f - y);
        }
    }

    const int rloc = lane >> 3;            // staging: row within 8-row group
    const int cg = (lane & 7) ^ rloc;      // staging: swizzled global chunk

    for (int kt = 0; kt < K / 64; ++kt) {
        const int kk = kt * 64;
        __syncthreads();
        // ---- stage A tile ----
        if constexpr (XSTAGE) {
            // VALU convert path (fp32 or bf16 -> fp16), same swizzled layout
#pragma unroll
            for (int p = 0; p < WM * 2; ++p) {
                const int s = p * 256 + tid;       // chunk id
                const int m = s >> 3, c = s & 7;
                const int g = c ^ (m & 7);
                f16x8 h;
                if (xf32) {
                    const float* gp = (const float*)xb + (long)(rowB + m) * ldx + kk + g * 8;
                    const float4 u = *(const float4*)gp;
                    const float4 u2 = *(const float4*)(gp + 4);
                    h[0] = (_Float16)u.x;  h[1] = (_Float16)u.y;
                    h[2] = (_Float16)u.z;  h[3] = (_Float16)u.w;
                    h[4] = (_Float16)u2.x; h[5] = (_Float16)u2.y;
                    h[6] = (_Float16)u2.z; h[7] = (_Float16)u2.w;
                } else {
                    const uint4 v = *(const uint4*)((const u16*)xb + (long)(rowB + m) * ldx + kk + g * 8);
                    const u16* pv = (const u16*)&v;
#pragma unroll
                    for (int j = 0; j < 8; ++j) h[j] = (_Float16)bf2f(pv[j]);
                }
                *(f16x8*)&As[s * 8] = h;
            }
        } else {
            const u16* xs = (const u16*)xb;
            int kkr = kk;
            if (kk >= ksplit) { xs += ksecond; kkr -= ksplit; }
#pragma unroll
            for (int s = wid; s < WM * 8; s += 4)
                gload16(xs + (long)(rowB + s * 8 + rloc) * ldx + kkr + cg * 8,
                        &As[s * 512 + lane * 8]);
        }
        // ---- stage B tile ----
#pragma unroll
        for (int s = wid; s < WN * 8; s += 4)
            gload16(wtp + (long)(nBase + s * 8 + rloc) * K + kk + cg * 8,
                    &Bs[s * 512 + lane * 8]);
        __syncthreads();

        // ---- compute ----
        const int sel = (ROWW && kk >= ksplit) ? 1 : 0;
#pragma unroll
        for (int q = 0; q < 2; ++q) {
            f16x8 af[4], bfr[4];
#pragma unroll
            for (int mi = 0; mi < 4; ++mi) {
                const int mm = wm * 64 + mi * 16 + fm;
                af[mi] = *(const f16x8*)&As[mm * 64 + (((q * 4 + quad) ^ (mm & 7)) * 8)];
            }
            if constexpr (ROWW) {
#pragma unroll
                for (int mi = 0; mi < 4; ++mi) {
                    const _Float16 yh = ysc[sel][mi];
#pragma unroll
                    for (int j = 0; j < 8; ++j) af[mi][j] *= yh;
                }
            }
#pragma unroll
            for (int ni = 0; ni < 4; ++ni) {
                const int nn = wn * 64 + ni * 16 + fm;
                bfr[ni] = *(const f16x8*)&Bs[nn * 64 + (((q * 4 + quad) ^ (nn & 7)) * 8)];
            }
#pragma unroll
            for (int mi = 0; mi < 4; ++mi)
#pragma unroll
                for (int ni = 0; ni < 4; ++ni)
                    acc[mi][ni] = __builtin_amdgcn_mfma_f32_16x16x32_f16(
                        af[mi], bfr[ni], acc[mi][ni], 0, 0, 0);
        }
    }

    __syncthreads();   // K-loop LDS dead from here; reuse as epilogue tiles

    // ---- epilogue phase 1: bias/relu/stats + transpose into wave's LDS ----
    // wave tile: u16[64][64], chunk-swizzled col ^= ((row>>1)&7)<<3
    u16* wtile = AsBs + wid * 4096;
    const int R0 = rowB + wm * 64;

    float yv[16];
    if constexpr (ROWW) {
        const float* yp = Y0v + (long)inst * B_ROWS;
#pragma unroll
        for (int mi = 0; mi < 4; ++mi)
#pragma unroll
            for (int r = 0; r < 4; ++r)
                yv[mi * 4 + r] = yp[R0 + mi * 16 + quad * 4 + r];
    }

#pragma unroll
    for (int ni = 0; ni < 4; ++ni) {
        const int nc = ni * 16 + fm;
        const int n = n0 + nc;
        float bS = 0.f, bP = 0.f, t0v = 0.f, t1v = 0.f;
        if constexpr (ROWW) {
            bP = biasP[(long)inst * bN + n];
            t0v = T0[(long)inst * bN + n];
            t1v = T1[(long)inst * bN + n];
        } else {
            bS = bsum[(long)inst * bN + n];
        }
        float s = 0.f, qq = 0.f;
#pragma unroll
        for (int mi = 0; mi < 4; ++mi) {
#pragma unroll
            for (int r = 0; r < 4; ++r) {
                float v;
                if constexpr (ROWW) {
                    const float y = yv[mi * 4 + r];
                    v = acc[mi][ni][r] + y * t0v + (1.f - y) * t1v + bP;
                } else {
                    v = acc[mi][ni][r] + bS;
                }
                v = fmaxf(v, 0.f);
                s += v; qq += v * v;
                const int lr = mi * 16 + quad * 4 + r;
                wtile[lr * 64 + (nc ^ (((lr >> 1) & 7) << 3))] = f2h(v);
            }
        }
        s += __shfl_xor(s, 16);  s += __shfl_xor(s, 32);
        qq += __shfl_xor(qq, 16); qq += __shfl_xor(qq, 32);
        if (quad == 0) { redS[wid][nc] = s; redQ[wid][nc] = qq; }
    }

    // ---- epilogue phase 2: coalesced 16B/lane stores from LDS ----
    {
        const int l8 = lane & 7, r8 = lane >> 3;
#pragma unroll
        for (int it = 0; it < 8; ++it) {
            const int lr = it * 8 + r8;
            const int ch = l8 ^ ((lr >> 1) & 7);
            const f16x8 hv = *(const f16x8*)&wtile[lr * 64 + ch * 8];
            *(f16x8*)(op + (long)(R0 + lr) * ldout + n0 + l8 * 8) = hv;
        }
    }

    __syncthreads();
    if (tid < WN * 64) {
        const int wnc = tid >> 6, within = tid & 63;
        float s = 0.f, q = 0.f;
#pragma unroll
        for (int w = 0; w < WM; ++w) {
            s += redS[w * WN + wnc][within];
            q += redQ[w * WN + wnc][within];
        }
        if (part) {
            // per-block partial (coalesced, no atomics); reduce_stats sums.
            float* pb = part +
                (long)((inst * gridDim.y + by) * gridDim.x + bx)
                    * (2 * WN * 64);
            pb[tid] = s;
            pb[WN * 64 + tid] = q;
        } else {
            atomicAdd(&gsum[(long)inst * sstride + nBase + tid], s);
            atomicAdd(&gsq [(long)inst * sstride + nBase + tid], q);
        }
    }
}

// ---------------------------------------------------------------------------
// gate_kernel: blocked GEMV, BN folded into LDS-resident scaled weights.
// Block = 256 threads = 128 rows x 2 col-segments (32 cols each).
// ---------------------------------------------------------------------------
__global__ __launch_bounds__(256) void gate_kernel(
    const u16* __restrict__ zc,
    const float* __restrict__ stFs, const float* __restrict__ stFq,
    const float* __restrict__ g4, const float* __restrict__ be4,
    const float* __restrict__ Wy, const float* __restrict__ by,
    float* __restrict__ Y0)
{
    const int tid = threadIdx.x;
    const int k = blockIdx.y;
    const int r0 = blockIdx.x * 128;

    __shared__ __align__(8) float Ws2[64][2];
    __shared__ float cg[2];

    // ---- fold BN into weights (one column per lane, first wave) ----
    if (tid < 64) {
        const int c = tid;
        const float m = stFs[k * 64 + c] * BINV;
        const float v = stFq[k * 64 + c] * BINV - m * m;
        const float s = g4[c] * rsqrtf(v + EPS_BN);
        const float t = be4[c] - m * s;
        const float w0 = Wy[k * 128 + c * 2 + 0];
        const float w1 = Wy[k * 128 + c * 2 + 1];
        Ws2[c][0] = s * w0;
        Ws2[c][1] = s * w1;
        float t0 = t * w0, t1 = t * w1;
#pragma unroll
        for (int off = 32; off; off >>= 1) {
            t0 += __shfl_xor(t0, off);
            t1 += __shfl_xor(t1, off);
        }
        if (c == 0) {
            cg[0] = t0 + by[k * 2 + 0];
            cg[1] = t1 + by[k * 2 + 1];
        }
    }
    __syncthreads();

    // ---- GEMV: 1 row / 2 threads, 32 columns each ----
    const int row = r0 + (tid >> 1);
    const int seg = tid & 1;
    const u16* xp = zc + ((long)k * B_ROWS + row) * 64 + seg * 32;
    float a0 = 0.f, a1 = 0.f;
#pragma unroll
    for (int it = 0; it < 4; ++it) {
        const uint4 v = *(const uint4*)(xp + it * 8);
        const u16* pv = (const u16*)&v;
#pragma unroll
        for (int e = 0; e < 8; ++e) {
            const int c = seg * 32 + it * 8 + e;
            const float x = h2f(pv[e]);
            a0 += x * Ws2[c][0];
            a1 += x * Ws2[c][1];
        }
    }
    a0 += __shfl_xor(a0, 1);
    a1 += __shfl_xor(a1, 1);
    if (seg == 0) {
        const float l0 = a0 + cg[0];
        const float l1 = a1 + cg[1];
        Y0[(long)k * B_ROWS + row] = 1.f / (1.f + __expf(l1 - l0));
    }
}

// ---------------------------------------------------------------------------
// heads_kernel: blocked GEMV, BN folded into LDS weight table Ws[256][8]
// (fp32, XOR-swizzled row index so 4 concurrent col-segments hit distinct
// bank groups). Block = 256 threads = 64 rows x 4 segments (64 cols).
// ---------------------------------------------------------------------------
__global__ __launch_bounds__(256) void heads_kernel(
    const u16* __restrict__ zxc,
    const float* __restrict__ stHs, const float* __restrict__ stHq,
    const float* __restrict__ g1, const float* __restrict__ be1,
    const float* __restrict__ Wo1, const float* __restrict__ bo1,
    const float* __restrict__ Wo2, const float* __restrict__ bo2,
    const float* __restrict__ Wo3, const float* __restrict__ bo3,
    const float* __restrict__ Wo4, const float* __restrict__ bo4,
    void* __restrict__ out, const int* __restrict__ dtflag)
{
    const int tid = threadIdx.x;
    const int k = blockIdx.y;
    const int r0 = blockIdx.x * 64;

    const float* Wo; const float* bo; int nk; long obase;
    if (k == 0)      { Wo = Wo1; bo = bo1; nk = 3; obase = 0; }
    else if (k == 1) { Wo = Wo2; bo = bo2; nk = 3; obase = (long)3 * B_ROWS; }
    else if (k == 2) { Wo = Wo3; bo = bo3; nk = 6; obase = (long)6 * B_ROWS; }
    else             { Wo = Wo4; bo = bo4; nk = 4; obase = (long)12 * B_ROWS; }

    __shared__ __align__(16) float Ws[256][8];
    __shared__ float cj[8];
    __shared__ float redC[4][8];

    // ---- fold BN into weights (one column per thread) ----
    {
        const int c = tid;
        const float m = stHs[k * 256 + c] * BINV;
        const float v = stHq[k * 256 + c] * BINV - m * m;
        const float s = g1[c] * rsqrtf(v + EPS_BN);
        const float t = be1[c] - m * s;
        const int rs = c ^ (c >> 6);       // bank-group swizzle
        float tw[6];
#pragma unroll
        for (int j = 0; j < 6; ++j) {
            const float w = (j < nk) ? Wo[c * nk + j] : 0.f;
            Ws[rs][j] = s * w;
            tw[j] = t * w;
        }
        Ws[rs][6] = 0.f; Ws[rs][7] = 0.f;
#pragma unroll
        for (int off = 32; off; off >>= 1)
#pragma unroll
            for (int j = 0; j < 6; ++j) tw[j] += __shfl_xor(tw[j], off);
        const int lane = tid & 63, wid = tid >> 6;
        if (lane < 6) redC[wid][lane] = tw[lane];
    }
    __syncthreads();
    if (tid < 8) {
        float s4 = 0.f;
        if (tid < 6) s4 = redC[0][tid] + redC[1][tid] + redC[2][tid] + redC[3][tid];
        cj[tid] = (tid < nk) ? s4 + bo[tid] : 0.f;
    }
    __syncthreads();

    // ---- GEMV: 1 row / 4 threads, 64 columns each ----
    const int row = r0 + (tid >> 2);
    const int seg = tid & 3;
    const u16* xp = zxc + ((long)k * B_ROWS + row) * 256 + seg * 64;
    float acc[6];
#pragma unroll
    for (int j = 0; j < 6; ++j) acc[j] = 0.f;
#pragma unroll
    for (int it = 0; it < 8; ++it) {
        const uint4 v = *(const uint4*)(xp + it * 8);
        const u16* pv = (const u16*)&v;
#pragma unroll
        for (int e = 0; e < 8; ++e) {
            const int cc = it * 8 + e;             // column within segment
            const int rs = (seg * 64 + cc) ^ seg;  // swizzled LDS row
            const float x = h2f(pv[e]);
            const f32x4 w0 = *(const f32x4*)&Ws[rs][0];
            const f32x4 w1 = *(const f32x4*)&Ws[rs][4];
            acc[0] += x * w0[0];
            acc[1] += x * w0[1];
            acc[2] += x * w0[2];
            acc[3] += x * w0[3];
            acc[4] += x * w1[0];
            acc[5] += x * w1[1];
        }
    }
#pragma unroll
    for (int j = 0; j < 6; ++j) {
        acc[j] += __shfl_xor(acc[j], 1);
        acc[j] += __shfl_xor(acc[j], 2);
    }

    if (seg == 0) {
        float l[6];
        float mx = -1e30f;
#pragma unroll
        for (int j = 0; j < 6; j++)
            if (j < nk) { l[j] = acc[j] + cj[j]; mx = fmaxf(mx, l[j]); }
        float e[6];
        float se = 0.f;
#pragma unroll
        for (int j = 0; j < 6; j++)
            if (j < nk) { e[j] = __expf(l[j] - mx); se += e[j]; }
        const float inv = 1.f / se;
        if (*dtflag) {
            u16* ob = (u16*)out;
#pragma unroll
            for (int j = 0; j < 6; j++)
                if (j < nk) ob[obase + (long)row * nk + j] = f2bf(e[j] * inv);
        } else {
            float* of = (float*)out;
#pragma unroll
            for (int j = 0; j < 6; j++)
                if (j < nk) of[obase + (long)row * nk + j] = e[j] * inv;
        }
    }
}

__global__ void fill_sentinel(u16* out, int n) {
    int i = blockIdx.x * 256 + threadIdx.x;
    if (i < n) out[i] = 0x3E80;
}

// ---------------------------------------------------------------------------
extern "C" void kernel_launch(void* const* d_in, const int* in_sizes, int n_in,
                              void* d_out, int out_size, void* d_ws, size_t ws_size,
                              hipStream_t stream)
{
    const long B = B_ROWS;
    char* ws = (char*)d_ws;
    const size_t MB = 1024 * 1024;

    // Lifetime-aliased activation layout (fp16)
    u16* z1  = (u16*)(ws);                      // [2][B][256]  (0..32MB)
    u16* z2  = (u16*)(ws + 32 * MB);            // [2][B][256]  (32..64MB)
    u16* za  = (u16*)(ws);                      // [4][B][128]  (0..32MB)
    u16* zbb = (u16*)(ws + 32 * MB);            // [4][B][64]   (32..48MB)
    u16* zc  = (u16*)(ws + 48 * MB);            // [4][B][64]   (48..64MB)
    u16* zxc = (u16*)(ws);                      // [4][B][256]  (0..64MB!)
    u16* zb  = (u16*)(ws + 64 * MB);            // [k][s][B][256] (64..192MB)
    float* Y0 = (float*)(ws + 192 * MB);                   // 512 KB
    float* stats = (float*)(ws + 192 * MB + 512 * 1024);   // 40 KB
    int* dtflag = (int*)(ws + 192 * MB + 576 * 1024);
    float* Pst = (float*)(ws + 192 * MB + 640 * 1024);     // small fp32 params

    // Wt region (fp16, prescaled+transposed weights)
    u16* WtA = (u16*)(ws + 193 * MB);                 // [256][512]     (+0..256KB)
    u16* WtB = WtA + 131072;                          // [2][256][256]  (+256..512KB)
    u16* WtC = WtB + 131072;                          // [8][256][256]  (+512KB..1.5MB)
    u16* WtD = WtC + 524288;                          // [4][128][512]  (+1.5..2MB)
    u16* WtH = WtD + 262144;                          // [4][256][512]  (+2..3MB)
    u16* WtE = WtH + 524288;                          // [4][64][128]
    u16* WtF = WtE + 32768;                           // [4][64][64]
    float* biasArea = (float*)(ws + 197 * MB);
    float* bA = biasArea;        // 2048
    float* bB = bA + 2048;       // 2048
    float* bC = bB + 2048;       // 8192
    float* bD = bC + 8192;       // 2048
    float* bH = bD + 2048;       // 4096
    float* bE = bH + 4096;       // 1024
    float* bF = bE + 1024;       // 1024

    // Stat-partial scratch in lifetime-dead regions:
    //  stage C partials: 4MB at ws+0 (z1 dead after B; za written at D,
    //    after reduce_stats(C)).  SAFE.
    //  stage H partials: 2MB at ws+193MB = WtA..WtD, all dead by stage H.
    float* partC = (float*)(ws);
    float* partH = (float*)(ws + 193 * MB);

    // fp32 param staging (gate/heads consumers)
    const int cIdx[20] = {6,7,10,11,12,13,20,21,22,23,24,25,28,29,30,31,32,33,34,35};
    PTab tab;
    int mapOff[36];
    int acc = 0;
    for (int i = 0; i < 20; i++) {
        tab.p[i] = d_in[cIdx[i]];
        tab.n[i] = in_sizes[cIdx[i]];
        tab.off[i] = acc;
        mapOff[cIdx[i]] = acc;
        acc += in_sizes[cIdx[i]];
    }
    const size_t need = 197 * MB + 20480 * 4 + 4096;
    if (need > ws_size || (size_t)acc * 4 > 384 * 1024) {
        fill_sentinel<<<(out_size + 255) / 256, 256, 0, stream>>>((u16*)d_out, out_size);
        return;
    }
    auto PF = [&](int idx) { return Pst + mapOff[idx]; };

    float* stAs = stats;        float* stAq = stAs + 512;   // [2][256]
    float* stBs = stAq + 512;   float* stBq = stBs + 512;   // [2][256]
    float* stCs = stBq + 512;   float* stCq = stCs + 2048;  // [k][s][256]
    float* stDs = stCq + 2048;  float* stDq = stDs + 512;   // [4][128]
    float* stEs = stDq + 512;   float* stEq = stEs + 256;   // [4][64]
    float* stFs = stEq + 256;   float* stFq = stFs + 256;   // [4][64]
    float* stHs = stFq + 256;   float* stHq = stHs + 1024;  // [4][256]

    hipMemsetAsync(stats, 0, 10240 * 4, stream);
    detect_dtype<<<1, 64, 0, stream>>>((const u16*)d_in[0], dtflag);
    convert_params<<<dim3(32, 20), 256, 0, stream>>>(tab, Pst, dtflag);

    const dim3 blk(256);
    const int BIGK = 1 << 29;  // "never split"

    // ---- Stage A: trunk L1 (dual-dtype X, VALU staging; RMODE 2) ---------
    prep_w<<<dim3(256, 2), blk, 0, stream>>>(
        d_in[2], 0, d_in[3], 0, nullptr, nullptr, 0, nullptr, nullptr, 0,
        dtflag, WtA, 0, bA, bA + 512, bA + 1024, bA + 1536, 256, 512, 512);
    gemm_mfma<true, false, 2, 2, 512, 2><<<dim3(256, 2, 2), blk, 0, stream>>>(
        d_in[0], d_in[1], 0, 0, 512, BIGK, 0, dtflag, WtA, 0,
        bA, bA + 512, bA + 1024, bA + 1536, 256,
        z1, B * 256, 256, stAs, stAq, 256, nullptr, nullptr);

    // ---- Stage B: trunk L2 (norm stA + g1/be1; RMODE 2) ------------------
    prep_w<<<dim3(256, 2), blk, 0, stream>>>(
        d_in[4], 0, d_in[5], 0, stAs, stAq, 256, d_in[6], d_in[7], 255,
        dtflag, WtB, 65536, bB, bB + 512, bB + 1024, bB + 1536, 256, 256, 256);
    gemm_mfma<false, false, 2, 2, 256, 2><<<dim3(256, 2, 2), blk, 0, stream>>>(
        z1, nullptr, B * 256, 3, 256, BIGK, 0, dtflag, WtB, 65536,
        bB, bB + 512, bB + 1024, bB + 1536, 256,
        z2, B * 256, 256, stBs, stBq, 256, nullptr, nullptr);

    // ---- Stage C: 8 branch projections (RMODE 1: insts share A) ----------
    for (int s = 0; s < 2; s++) {
        prep_w<<<dim3(256, 4), blk, 0, stream>>>(
            d_in[s ? 16 : 14], 65536, d_in[s ? 17 : 15], 256,
            stBs + s * 256, stBq + s * 256, 0, d_in[8], d_in[9], 255,
            dtflag, WtC + s * 65536, 131072,
            bC + s * 256, bC + 2048 + s * 256, bC + 4096 + s * 256,
            bC + 6144 + s * 256, 512, 256, 256);
    }
    gemm_mfma<false, false, 2, 2, 256, 1><<<dim3(256, 2, 8), blk, 0, stream>>>(
        z2, nullptr, B * 256, 1, 256, BIGK, 0, dtflag, WtC, 65536,
        bC, bC + 2048, bC + 4096, bC + 6144, 256,
        zb, B * 256, 256, stCs, stCq, 256, partC, nullptr);
    reduce_stats<<<dim3(8), blk, 0, stream>>>(partC, 256, 128, stCs, stCq, 2048);

    // ---- Stage D prep+gemm, H prep (RMODE 0: per-inst A streaming) -------
    prep_w<<<dim3(128, 4), blk, 0, stream>>>(
        d_in[18], 65536, d_in[19], 128, stCs, stCq, 512, d_in[6], d_in[7], 255,
        dtflag, WtD, 65536, bD, bD + 512, bD + 1024, bD + 1536, 128, 512, 512);
    prep_w<<<dim3(256, 4), blk, 0, stream>>>(
        d_in[26], 131072, d_in[27], 256, stCs, stCq, 512, d_in[6], d_in[7], 255,
        dtflag, WtH, 131072, bH, bH + 1024, bH + 2048, bH + 3072, 256, 512, 256);
    gemm_mfma<false, false, 2, 2, 512, 0><<<dim3(256, 1, 4), blk, 0, stream>>>(
        zb, nullptr, 2 * B * 256, 3, 256, 256, B * 256, dtflag, WtD, 65536,
        bD, bD + 512, bD + 1024, bD + 1536, 128,
        za, B * 128, 128, stDs, stDq, 128, nullptr, nullptr);

    // ---- Stage E: gating layer b (RMODE 0) -------------------------------
    prep_w<<<dim3(64, 4), blk, 0, stream>>>(
        d_in[20], 8192, d_in[21], 64, stDs, stDq, 128, d_in[10], d_in[11], 127,
        dtflag, WtE, 8192, bE, bE + 256, bE + 512, bE + 768, 64, 128, 128);
    gemm_mfma<false, false, 4, 1, 128, 0><<<dim3(128, 1, 4), blk, 0, stream>>>(
        za, nullptr, B * 128, 3, 128, BIGK, 0, dtflag, WtE, 8192,
        bE, bE + 256, bE + 512, bE + 768, 64,
        zbb, B * 64, 64, stEs, stEq, 64, nullptr, nullptr);

    // ---- Stage F: gating layer c (RMODE 0) -------------------------------
    prep_w<<<dim3(64, 4), blk, 0, stream>>>(
        d_in[22], 4096, d_in[23], 64, stEs, stEq, 64, d_in[12], d_in[13], 63,
        dtflag, WtF, 4096, bF, bF + 256, bF + 512, bF + 768, 64, 64, 64);
    gemm_mfma<false, false, 4, 1, 64, 0><<<dim3(128, 1, 4), blk, 0, stream>>>(
        zbb, nullptr, B * 64, 3, 64, BIGK, 0, dtflag, WtF, 4096,
        bF, bF + 256, bF + 512, bF + 768, 64,
        zc, B * 64, 64, stFs, stFq, 64, nullptr, nullptr);

    // ---- Gate (blocked GEMV, 128 rows/block) -----------------------------
    gate_kernel<<<dim3(B_ROWS / 128, 4), blk, 0, stream>>>(
        zc, stFs, stFq, PF(12), PF(13), PF(24), PF(25), Y0);

    // ---- Stage H: combine (RMODE 2: share across y only) -----------------
    gemm_mfma<false, true, 2, 2, 512, 2><<<dim3(256, 2, 4), blk, 0, stream>>>(
        zb, nullptr, 2 * B * 256, 3, 256, 256, B * 256, dtflag, WtH, 131072,
        bH, bH + 1024, bH + 2048, bH + 3072, 256,
        zxc, B * 256, 256, stHs, stHq, 256, partH, Y0);
    reduce_stats<<<dim3(4), blk, 0, stream>>>(partH, 256, 128, stHs, stHq, 1024);

    // ---- Output heads (blocked GEMV, 64 rows/block) ----------------------
    heads_kernel<<<dim3(B_ROWS / 64, 4), blk, 0, stream>>>(
        zxc, stHs, stHq, PF(6), PF(7), PF(28), PF(29), PF(30), PF(31),
        PF(32), PF(33), PF(34), PF(35), d_out, dtflag);
}